// Round 15
// baseline (605.697 us; speedup 1.0000x reference)
//
#include <hip/hip_runtime.h>
#include <hip/hip_bf16.h>
#include <hip/hip_fp16.h>

// ---------------- problem constants ----------------
#define BB 32
#define NN 20
#define TT 100
#define DD 4
#define HH 128
#define EE 380          // N*(N-1)
#define BE 12160        // B*E
#define L1 96           // conv1 out length
#define LP 48           // after maxpool
#define L2 44           // conv2 out length
#define NOUT 16
#define EPS 1e-5f
#define NREP 64         // stats replicas (atomic de-contention)

typedef _Float16 f16x8 __attribute__((ext_vector_type(8)));
typedef _Float16 f16x4 __attribute__((ext_vector_type(4)));
typedef _Float16 f16x2 __attribute__((ext_vector_type(2)));
typedef float f32x4 __attribute__((ext_vector_type(4)));

// stats slot indices (floats): SC at base, SH at base+128. Slots 0..127 = conv2 bias2 (BN1-fold).
#define S_BIAS2 0
#define S_BN1_SC 256
#define S_BN2_SC 768
#define S_M1_SC 1280
#define S_M2_SC 1792
#define S_M3_SC 2304

// workspace offsets (bytes)
#define OFF_STATS 0ULL
#define OFF_SIDX 16384ULL
#define OFF_RIDX 18432ULL
#define OFF_INC 20480ULL
#define OFF_Y23 24576ULL                     // f16 [BE] slots of 6144: y2pre [48][128] then y3 t-major [44][128]
#define OFF_X 149446656ULL                   // f32 [BE][128]
#define OFF_BUFA 155672576ULL                // f32 [BE][128]; rep1/rep2 live here during conv phase
#define OFF_BUFB 161898496ULL                // f32 [BE][128]
#define OFF_XN 168124416ULL                  // f32 [640][128]
#define OFF_T640 168452096ULL                // conv-phase: apack(160K)+apack1(16K)+pwt(64K)+w2sum(64K)
#define OFF_REPM 168779776ULL                // f32 [64][256] MLP stats replicas
#define OFF_HF16 168845312ULL                // f16 [BE][128] MLP intermediates (3.1 MB)
#define OFF_MP 171958272ULL                  // f16 MLP weight packs (256 KB)
#define OFF_APACK OFF_T640
#define OFF_APACK1 (OFF_T640 + 163840ULL)
#define OFF_PWT (OFF_T640 + 180224ULL)
#define OFF_W2SUM (OFF_T640 + 245760ULL)
#define OFF_REP1 OFF_BUFA
#define OFF_REP2 (OFF_BUFA + 65536ULL)
// MP pack offsets in f16 units
#define MP_M1W1 0
#define MP_M1W2 16384
#define MP_M2W1 32768
#define MP_M2W2 49152
#define MP_M3W2 65536
#define MP_M3W1 81920

__device__ __forceinline__ float eluf(float v) { return v > 0.f ? v : expm1f(v); }

// ---------------- K prep: pack all MFMA weights, transpose pred_w, w2 tap-sums, init tables ----------------
// conv1 A-pack K-order c' = k*8 + ci (direct-from-time-major B, no im2col).
__global__ __launch_bounds__(256) void k_prep(const float* __restrict__ rel_rec,
                                              const float* __restrict__ rel_send,
                                              const float* __restrict__ w2,
                                              const float* __restrict__ w1,
                                              const float* __restrict__ pred_w,
                                              const float* __restrict__ m1w1,
                                              const float* __restrict__ m1w2,
                                              const float* __restrict__ m2w1,
                                              const float* __restrict__ m2w2,
                                              const float* __restrict__ m3w1,
                                              const float* __restrict__ m3w2,
                                              _Float16* __restrict__ apack,
                                              _Float16* __restrict__ apack1,
                                              float* __restrict__ pwt,
                                              float* __restrict__ w2sum,
                                              _Float16* __restrict__ mp,
                                              float* rep1, float* rep2, float* repm,
                                              int* sidx, int* ridx, int* inc) {
    int b = blockIdx.x;
    int tid = threadIdx.x;
    int l = tid & 63;
    if (b < 40) {            // conv2_w frags (raw; BN1 scale applied later by k_scale)
        int f = b * 4 + (tid >> 6);
        int m0 = f & 7, ks = f >> 3, s = ks & 3, k = ks >> 2;
        int m = m0 * 16 + (l & 15);
        int cbase = 32 * s + (l >> 4) * 8;
#pragma unroll
        for (int j = 0; j < 8; ++j)
            apack[(f * 64 + l) * 8 + j] = (_Float16)w2[m * 640 + (cbase + j) * 5 + k];
    } else if (b < 44) {     // conv1_w frags: c' = k*8+ci, taps k>=5 zero-padded
        int f = (b - 40) * 4 + (tid >> 6);
        int m0 = f & 7, s = f >> 3;
        int m = m0 * 16 + (l & 15);
        int cbase = 32 * s + (l >> 4) * 8;
#pragma unroll
        for (int j = 0; j < 8; ++j) {
            int c = cbase + j;
            int k = c >> 3, ci = c & 7;
            apack1[(f * 64 + l) * 8 + j] = (k < 5) ? (_Float16)w1[m * 40 + ci * 5 + k]
                                                   : (_Float16)0.f;
        }
    } else if (b == 44) {    // init: zero replicas, build edge tables
        for (int i = tid; i < NREP * 256; i += 256) { rep1[i] = 0.f; rep2[i] = 0.f; repm[i] = 0.f; }
        for (int e = tid; e < EE; e += 256) {
            int s = 0, r = 0;
            for (int n = 0; n < NN; ++n) {
                if (rel_send[e * NN + n] > 0.5f) s = n;
                if (rel_rec[e * NN + n] > 0.5f) r = n;
            }
            sidx[e] = s; ridx[e] = r;
        }
        __syncthreads();
        if (tid < NN) {
            int k = 0;
            for (int e = 0; e < EE; ++e)
                if (ridx[e] == tid) inc[tid * (NN - 1) + (k++)] = e;
        }
    } else if (b < 53) {     // transpose pred_w -> pwt[c][o]
        int idx = (b - 45) * 2048 + tid;
        for (int rep = 0; rep < 8; ++rep, idx += 256) {
            int o = idx >> 7, c = idx & 127;
            pwt[c * 128 + o] = pred_w[idx];
        }
    } else if (b < 117) {    // MLP weight packs: generic [128][K] -> A-frag-linear
        int idx = b - 53;    // 0..63
        const float* W; _Float16* dst; int K;
        if (idx < 8)       { W = m1w1; dst = mp + MP_M1W1; K = 128; }
        else if (idx < 16) { W = m1w2; dst = mp + MP_M1W2; K = 128; idx -= 8; }
        else if (idx < 24) { W = m2w1; dst = mp + MP_M2W1; K = 128; idx -= 16; }
        else if (idx < 32) { W = m2w2; dst = mp + MP_M2W2; K = 128; idx -= 24; }
        else if (idx < 40) { W = m3w2; dst = mp + MP_M3W2; K = 128; idx -= 32; }
        else               { W = m3w1; dst = mp + MP_M3W1; K = 384; idx -= 40; }
        int f = idx * 4 + (tid >> 6);
        int s = f >> 3, m0 = f & 7;
        int m = m0 * 16 + (l & 15);
        int cb = 32 * s + (l >> 4) * 8;
#pragma unroll
        for (int j = 0; j < 8; ++j)
            dst[(f * 64 + l) * 8 + j] = (_Float16)W[m * K + cb + j];
    } else {                 // w2 tap-sums: w2sum[co][ci] = sum_k w2[co][ci][k]
        int idx = (b - 117) * 2048 + tid;
        for (int rep = 0; rep < 8; ++rep, idx += 256) {
            const float* wr = w2 + idx * 5;
            w2sum[idx] = wr[0] + wr[1] + wr[2] + wr[3] + wr[4];
        }
    }
}

// ---------------- K1: conv1 (MFMA, direct-from-LDS B) + relu -> BN1 stats + PRE-BN maxpool ----------------
// pool-before-BN exact: bn1_g=1 -> BN scale>0 -> max commutes with fma.
__global__ __launch_bounds__(256) void k_conv1_stats(const float* __restrict__ inputs,
                                                     const _Float16* __restrict__ apack1,
                                                     const float* __restrict__ conv1_b,
                                                     const int* __restrict__ sidx,
                                                     const int* __restrict__ ridx,
                                                     float* rep1,
                                                     _Float16* __restrict__ y2p) {
    __shared__ __align__(16) _Float16 s_edgesT[104 * 8];
    __shared__ __align__(16) _Float16 s_y2t[48 * 136];
    int be = blockIdx.x;
    int b = be / EE, e = be - b * EE;
    int sn = sidx[e], rn = ridx[e];
    float* rep = rep1 + (be & (NREP - 1)) * 256;
    for (int i = threadIdx.x; i < 200; i += 256) {
        int side = (i >= 100) ? 1 : 0;
        int t = i - side * 100;
        int n = side ? rn : sn;
        float4 v = *(const float4*)(inputs + ((long long)(b * NN + n) * TT + t) * DD);
        f16x4 o = {(_Float16)v.x, (_Float16)v.y, (_Float16)v.z, (_Float16)v.w};
        *(f16x4*)(&s_edgesT[t * 8 + side * 4]) = o;
    }
    if (threadIdx.x < 32) s_edgesT[800 + threadIdx.x] = (_Float16)0.f;
    __syncthreads();
    int w = threadIdx.x >> 6, lane = threadIdx.x & 63;
    int quad = lane >> 4, l15 = lane & 15;
    f32x4 acc1[2][6];
#pragma unroll
    for (int m = 0; m < 2; ++m)
#pragma unroll
        for (int nt = 0; nt < 6; ++nt) acc1[m][nt] = (f32x4){0.f, 0.f, 0.f, 0.f};
    {
        const f16x8* Ap = (const f16x8*)apack1;
#pragma unroll
        for (int s = 0; s < 2; ++s) {
            f16x8 a0 = Ap[(s * 8 + 2 * w) * 64 + lane];
            f16x8 a1 = Ap[(s * 8 + 2 * w + 1) * 64 + lane];
#pragma unroll
            for (int nt = 0; nt < 6; ++nt) {
                f16x8 bfr = *(const f16x8*)(&s_edgesT[(nt * 16 + l15 + 4 * s + quad) * 8]);
                acc1[0][nt] = __builtin_amdgcn_mfma_f32_16x16x32_f16(a0, bfr, acc1[0][nt], 0, 0, 0);
                acc1[1][nt] = __builtin_amdgcn_mfma_f32_16x16x32_f16(a1, bfr, acc1[1][nt], 0, 0, 0);
            }
        }
    }
#pragma unroll
    for (int m = 0; m < 2; ++m) {
        int co0 = (2 * w + m) * 16 + quad * 4;
        float ss[4] = {0.f, 0.f, 0.f, 0.f}, qq[4] = {0.f, 0.f, 0.f, 0.f};
#pragma unroll
        for (int nt = 0; nt < 6; ++nt) {
            int t = nt * 16 + l15;
#pragma unroll
            for (int r = 0; r < 4; ++r) {
                float v = fmaxf(acc1[m][nt][r] + conv1_b[co0 + r], 0.f);
                ss[r] += v; qq[r] += v * v;
                float p = __shfl_xor(v, 1);
                if ((l15 & 1) == 0)
                    s_y2t[(t >> 1) * 136 + co0 + r] = (_Float16)fmaxf(v, p);
            }
        }
#pragma unroll
        for (int r = 0; r < 4; ++r) {
            float s = ss[r], q = qq[r];
            s += __shfl_xor(s, 1); s += __shfl_xor(s, 2); s += __shfl_xor(s, 4); s += __shfl_xor(s, 8);
            q += __shfl_xor(q, 1); q += __shfl_xor(q, 2); q += __shfl_xor(q, 4); q += __shfl_xor(q, 8);
            if (l15 == 0) {
                atomicAdd(&rep[co0 + r], s);
                atomicAdd(&rep[128 + co0 + r], q);
            }
        }
    }
    __syncthreads();
    _Float16* dst = y2p + (long long)be * 6144;
    for (int chunk = threadIdx.x; chunk < 768; chunk += 256) {
        int row = chunk >> 4, off = (chunk & 15) * 8;
        *(f16x8*)(dst + row * 128 + off) = *(const f16x8*)(&s_y2t[row * 136 + off]);
    }
}

// ---------------- finalize BN from 64 replicas -> scale/shift (re-zero replicas) ----------------
__global__ void k_finalize_rep(float* __restrict__ rep, float* stats, int scIdx,
                               const float* __restrict__ g, const float* __restrict__ bb,
                               float inv_count) {
    int j = threadIdx.x;
    float s = 0.f, q = 0.f;
    for (int i = 0; i < NREP; ++i) {
        s += rep[i * 256 + j];
        q += rep[i * 256 + 128 + j];
    }
    for (int i = 0; i < NREP; ++i) {
        rep[i * 256 + j] = 0.f;
        rep[i * 256 + 128 + j] = 0.f;
    }
    float m = s * inv_count;
    float v = fmaxf(q * inv_count - m * m, 0.f);
    float sc = g[j] * rsqrtf(v + EPS);
    stats[scIdx + j] = sc;
    stats[scIdx + 128 + j] = bb[j] - m * sc;
}

// ---------------- finalize BN1 + conv2 fused bias2[co] = conv2_b + sum_ci w2sum*sh ----------------
// Valid: every conv2 output t uses all 5 taps (VALID conv over 48 rows).
__global__ void k_finalize_bn1(float* __restrict__ rep, float* stats,
                               const float* __restrict__ g, const float* __restrict__ bb,
                               const float* __restrict__ w2sum, const float* __restrict__ conv2_b,
                               float inv_count) {
    __shared__ float s_sh[128];
    int j = threadIdx.x;  // 128
    float s = 0.f, q = 0.f;
    for (int i = 0; i < NREP; ++i) {
        s += rep[i * 256 + j];
        q += rep[i * 256 + 128 + j];
    }
    for (int i = 0; i < NREP; ++i) {
        rep[i * 256 + j] = 0.f;
        rep[i * 256 + 128 + j] = 0.f;
    }
    float m = s * inv_count;
    float v = fmaxf(q * inv_count - m * m, 0.f);
    float sc = g[j] * rsqrtf(v + EPS);
    float sh = bb[j] - m * sc;
    stats[S_BN1_SC + j] = sc;
    stats[S_BN1_SC + 128 + j] = sh;
    s_sh[j] = sh;
    __syncthreads();
    float acc = conv2_b[j];
    for (int ci = 0; ci < 128; ++ci)
        acc = fmaf(w2sum[j * 128 + ci], s_sh[ci], acc);
    stats[S_BIAS2 + j] = acc;
}

// ---------------- K scale: apack *= BN1 scale (per input channel), in place ----------------
// Deterministic per call: k_prep rewrites apack raw before this every launch.
__global__ __launch_bounds__(256) void k_scale(_Float16* __restrict__ apack,
                                               const float* __restrict__ stats) {
    int tid = threadIdx.x, l = tid & 63;
    int f = blockIdx.x * 4 + (tid >> 6);
    int s = (f >> 3) & 3;
    int cbase = 32 * s + (l >> 4) * 8;
    _Float16* p = apack + (f * 64 + l) * 8;
#pragma unroll
    for (int j = 0; j < 8; ++j)
        p[j] = (_Float16)((float)p[j] * stats[S_BN1_SC + cbase + j]);
}

// ---------------- K3: 1 edge/block (14.1KB LDS -> 8 blocks/CU, full 32-wave occupancy);
// raw y2pre -> LDS (pure copy), conv2 MFMA (BN1 folded in A) -> y3 t-major + BN2 stats.
// [LDS staging is load-bearing: R13's LDS-free variant regressed 148->276 us. Do not remove.]
// [L2 A-frag issued traffic is identical for 1-edge vs 2-edge blocks; occupancy is the lever.]
__global__ __launch_bounds__(256) void k_conv2(_Float16* __restrict__ y23,
                                               const _Float16* __restrict__ apack,
                                               const float* __restrict__ stats,
                                               float* rep2) {
    __shared__ __align__(16) _Float16 s_y2t[52 * 136];
    int tid = threadIdx.x;
    int be = blockIdx.x;
    if (tid < 272) ((int*)(&s_y2t[48 * 136]))[tid] = 0;
    for (int i = tid; i < 768; i += 256) {
        int row = i >> 4, c0 = (i & 15) * 8;
        *(f16x8*)(&s_y2t[row * 136 + c0]) =
            *(const f16x8*)(y23 + (long long)be * 6144 + i * 8);
    }
    __syncthreads();
    int w = tid >> 6, lane = tid & 63;
    int quad = lane >> 4, l15 = lane & 15;
    f32x4 acc[2][3];
#pragma unroll
    for (int m = 0; m < 2; ++m)
#pragma unroll
        for (int nt = 0; nt < 3; ++nt) acc[m][nt] = (f32x4){0.f, 0.f, 0.f, 0.f};
    const f16x8* Ap = (const f16x8*)apack;
#pragma unroll
    for (int k = 0; k < 5; ++k) {
#pragma unroll
        for (int s = 0; s < 4; ++s) {
            f16x8 a0 = Ap[((k * 4 + s) * 8 + 2 * w) * 64 + lane];
            f16x8 a1 = Ap[((k * 4 + s) * 8 + 2 * w + 1) * 64 + lane];
#pragma unroll
            for (int nt = 0; nt < 3; ++nt) {
                f16x8 bfr = *(const f16x8*)((const char*)s_y2t +
                                            (nt * 16 + l15 + k) * 272 + 64 * s + quad * 16);
                acc[0][nt] = __builtin_amdgcn_mfma_f32_16x16x32_f16(a0, bfr, acc[0][nt], 0, 0, 0);
                acc[1][nt] = __builtin_amdgcn_mfma_f32_16x16x32_f16(a1, bfr, acc[1][nt], 0, 0, 0);
            }
        }
    }
    // epilogue: bias2 + relu, store y3 t-major [44][128] (f16x4), BN2 stats
    _Float16* y3 = y23 + (long long)be * 6144;
    float* rep = rep2 + (be & (NREP - 1)) * 256;
#pragma unroll
    for (int m = 0; m < 2; ++m) {
        int co0 = (2 * w + m) * 16 + quad * 4;
        float4 bs = *(const float4*)(stats + S_BIAS2 + co0);
        float ssum[4] = {0.f, 0.f, 0.f, 0.f}, qsum[4] = {0.f, 0.f, 0.f, 0.f};
#pragma unroll
        for (int nt = 0; nt < 3; ++nt) {
            int t = nt * 16 + l15;
            if (t < 44) {
                float v0 = fmaxf(acc[m][nt][0] + bs.x, 0.f);
                float v1 = fmaxf(acc[m][nt][1] + bs.y, 0.f);
                float v2 = fmaxf(acc[m][nt][2] + bs.z, 0.f);
                float v3 = fmaxf(acc[m][nt][3] + bs.w, 0.f);
                f16x4 o = {(_Float16)v0, (_Float16)v1, (_Float16)v2, (_Float16)v3};
                *(f16x4*)(y3 + t * 128 + co0) = o;
                ssum[0] += v0; qsum[0] += v0 * v0;
                ssum[1] += v1; qsum[1] += v1 * v1;
                ssum[2] += v2; qsum[2] += v2 * v2;
                ssum[3] += v3; qsum[3] += v3 * v3;
            }
        }
#pragma unroll
        for (int r = 0; r < 4; ++r) {
            float s = ssum[r], q = qsum[r];
            s += __shfl_xor(s, 1); s += __shfl_xor(s, 2); s += __shfl_xor(s, 4); s += __shfl_xor(s, 8);
            q += __shfl_xor(q, 1); q += __shfl_xor(q, 2); q += __shfl_xor(q, 4); q += __shfl_xor(q, 8);
            if (l15 == 0) {
                atomicAdd(&rep[co0 + r], s);
                atomicAdd(&rep[128 + co0 + r], q);
            }
        }
    }
}

// ---------------- K5: BN2 apply + attention-pool -> x [BE][128] (y3 t-major input) ----------------
__global__ __launch_bounds__(256) void k_predatt(const _Float16* __restrict__ y23,
                                                 const float* __restrict__ stats,
                                                 const float* __restrict__ att_w,
                                                 const float* __restrict__ att_b,
                                                 const float* __restrict__ pwt,
                                                 const float* __restrict__ pred_b,
                                                 float* __restrict__ x) {
    __shared__ float h[44 * 132];   // h[t][c], stride 132 (pad 4)
    __shared__ float s_att[48];
    __shared__ float s_p1[256];
    __shared__ float s_p2[256];
    __shared__ float s_sc[128], s_sh[128];
    int be = blockIdx.x, tid = threadIdx.x;
    if (tid < 128) {
        s_sc[tid] = stats[S_BN2_SC + tid];
        s_sh[tid] = stats[S_BN2_SC + 128 + tid];
    }
    __syncthreads();
    const _Float16* yp = y23 + (long long)be * 6144;
    for (int i = tid; i < 704; i += 256) {   // 44 rows x 16 chunks of 8
        int t = i >> 4, c0 = (i & 15) * 8;
        f16x8 v = *(const f16x8*)(yp + i * 8);
        float4 a, bq;
        a.x = fmaf((float)v[0], s_sc[c0 + 0], s_sh[c0 + 0]);
        a.y = fmaf((float)v[1], s_sc[c0 + 1], s_sh[c0 + 1]);
        a.z = fmaf((float)v[2], s_sc[c0 + 2], s_sh[c0 + 2]);
        a.w = fmaf((float)v[3], s_sc[c0 + 3], s_sh[c0 + 3]);
        bq.x = fmaf((float)v[4], s_sc[c0 + 4], s_sh[c0 + 4]);
        bq.y = fmaf((float)v[5], s_sc[c0 + 5], s_sh[c0 + 5]);
        bq.z = fmaf((float)v[6], s_sc[c0 + 6], s_sh[c0 + 6]);
        bq.w = fmaf((float)v[7], s_sc[c0 + 7], s_sh[c0 + 7]);
        *(float4*)(&h[t * 132 + c0]) = a;
        *(float4*)(&h[t * 132 + c0 + 4]) = bq;
    }
    __syncthreads();
    int w = tid >> 6, lane = tid & 63;
    {
        float aw0 = att_w[lane], aw1 = att_w[64 + lane];
        for (int tt = 0; tt < 11; ++tt) {
            int t = w * 11 + tt;
            float p = h[t * 132 + lane] * aw0 + h[t * 132 + 64 + lane] * aw1;
            p += __shfl_xor(p, 1); p += __shfl_xor(p, 2); p += __shfl_xor(p, 4);
            p += __shfl_xor(p, 8); p += __shfl_xor(p, 16); p += __shfl_xor(p, 32);
            if (lane == 0) s_att[t] = p + att_b[0];
        }
    }
    __syncthreads();
    if (w == 0) {
        float v = (lane < 44) ? s_att[lane] : -1e30f;
        float m = v;
        m = fmaxf(m, __shfl_xor(m, 1)); m = fmaxf(m, __shfl_xor(m, 2));
        m = fmaxf(m, __shfl_xor(m, 4)); m = fmaxf(m, __shfl_xor(m, 8));
        m = fmaxf(m, __shfl_xor(m, 16)); m = fmaxf(m, __shfl_xor(m, 32));
        float ev = (lane < 44) ? expf(v - m) : 0.f;
        float ss = ev;
        ss += __shfl_xor(ss, 1); ss += __shfl_xor(ss, 2); ss += __shfl_xor(ss, 4);
        ss += __shfl_xor(ss, 8); ss += __shfl_xor(ss, 16); ss += __shfl_xor(ss, 32);
        if (lane < 44) s_att[lane] = ev / ss;
    }
    __syncthreads();
    {
        int c = tid & 127, hh = tid >> 7;
        float a = 0.f;
        for (int t = hh * 22; t < hh * 22 + 22; ++t) a = fmaf(h[t * 132 + c], s_att[t], a);
        s_p1[tid] = a;
    }
    __syncthreads();
    {
        int o = tid & 127, hh = tid >> 7;
        float a = 0.f;
        for (int c = hh * 64; c < hh * 64 + 64; ++c) {
            float hw = s_p1[c] + s_p1[128 + c];
            a = fmaf(pwt[c * 128 + o], hw, a);
        }
        s_p2[tid] = a;
    }
    __syncthreads();
    if (tid < 128) {
        float a = s_p2[tid] + s_p2[128 + tid] + pred_b[tid];
        x[(long long)be * 128 + tid] = a * (1.0f / 44.0f);
    }
}

// ---------------- MFMA linear (128 -> 128), 64 rows/block ----------------
template <bool IN16, bool OUT16, bool STATS>
__global__ __launch_bounds__(256) void k_linmm(const void* __restrict__ inV,
                                               const _Float16* __restrict__ wp,
                                               const float* __restrict__ bias,
                                               void* __restrict__ outV,
                                               float* __restrict__ repm) {
    __shared__ __align__(16) _Float16 s_b[64 * 136];
    int tid = threadIdx.x;
    long long r0 = (long long)blockIdx.x * 64;
    if (IN16) {
        const f16x8* src = (const f16x8*)((const _Float16*)inV + r0 * 128);
        for (int i = tid; i < 1024; i += 256) {
            int row = i >> 4, c0 = (i & 15) * 8;
            *(f16x8*)(&s_b[row * 136 + c0]) = src[i];
        }
    } else {
        const float4* src = (const float4*)((const float*)inV + r0 * 128);
        for (int i = tid; i < 2048; i += 256) {
            int row = i >> 5, c0 = (i & 31) * 4;
            float4 v = src[i];
            f16x4 o = {(_Float16)v.x, (_Float16)v.y, (_Float16)v.z, (_Float16)v.w};
            *(f16x4*)(&s_b[row * 136 + c0]) = o;
        }
    }
    __syncthreads();
    int w = tid >> 6, lane = tid & 63, quad = lane >> 4, l15 = lane & 15;
    f32x4 acc[2][4];
#pragma unroll
    for (int m = 0; m < 2; ++m)
#pragma unroll
        for (int nt = 0; nt < 4; ++nt) acc[m][nt] = (f32x4){0.f, 0.f, 0.f, 0.f};
    const f16x8* Ap = (const f16x8*)wp;
#pragma unroll
    for (int s = 0; s < 4; ++s) {
        f16x8 a0 = Ap[(s * 8 + 2 * w) * 64 + lane];
        f16x8 a1 = Ap[(s * 8 + 2 * w + 1) * 64 + lane];
#pragma unroll
        for (int nt = 0; nt < 4; ++nt) {
            f16x8 bfr = *(const f16x8*)((const char*)s_b + (nt * 16 + l15) * 272 + 64 * s + quad * 16);
            acc[0][nt] = __builtin_amdgcn_mfma_f32_16x16x32_f16(a0, bfr, acc[0][nt], 0, 0, 0);
            acc[1][nt] = __builtin_amdgcn_mfma_f32_16x16x32_f16(a1, bfr, acc[1][nt], 0, 0, 0);
        }
    }
#pragma unroll
    for (int m = 0; m < 2; ++m) {
        int j0 = (2 * w + m) * 16 + quad * 4;
        float4 bs = *(const float4*)(bias + j0);
        float ss[4] = {0.f, 0.f, 0.f, 0.f}, qq[4] = {0.f, 0.f, 0.f, 0.f};
#pragma unroll
        for (int nt = 0; nt < 4; ++nt) {
            int row = nt * 16 + l15;
            float v0 = eluf(acc[m][nt][0] + bs.x);
            float v1 = eluf(acc[m][nt][1] + bs.y);
            float v2 = eluf(acc[m][nt][2] + bs.z);
            float v3 = eluf(acc[m][nt][3] + bs.w);
            if (OUT16) {
                f16x4 o = {(_Float16)v0, (_Float16)v1, (_Float16)v2, (_Float16)v3};
                *(f16x4*)((_Float16*)outV + (r0 + row) * 128 + j0) = o;
            } else {
                float4 o = {v0, v1, v2, v3};
                *(float4*)((float*)outV + (r0 + row) * 128 + j0) = o;
            }
            if (STATS) {
                ss[0] += v0; qq[0] += v0 * v0;
                ss[1] += v1; qq[1] += v1 * v1;
                ss[2] += v2; qq[2] += v2 * v2;
                ss[3] += v3; qq[3] += v3 * v3;
            }
        }
        if (STATS) {
            float* rep = repm + (blockIdx.x & (NREP - 1)) * 256;
#pragma unroll
            for (int r = 0; r < 4; ++r) {
                float s = ss[r], q = qq[r];
                s += __shfl_xor(s, 1); s += __shfl_xor(s, 2); s += __shfl_xor(s, 4); s += __shfl_xor(s, 8);
                q += __shfl_xor(q, 1); q += __shfl_xor(q, 2); q += __shfl_xor(q, 4); q += __shfl_xor(q, 8);
                if (l15 == 0) {
                    atomicAdd(&rep[j0 + r], s);
                    atomicAdd(&rep[128 + j0 + r], q);
                }
            }
        }
    }
}

// ---------------- MFMA mlp3 l1: gather-concat [send|recv|skip] (K=384) -> 128 f16 ----------------
__global__ __launch_bounds__(256) void k_linmm3(const float* __restrict__ xn,
                                                const float* __restrict__ bufB,
                                                const int* __restrict__ sidx,
                                                const int* __restrict__ ridx,
                                                const float* __restrict__ stats,
                                                const _Float16* __restrict__ wp,
                                                const float* __restrict__ bias,
                                                _Float16* __restrict__ out) {
    __shared__ __align__(16) _Float16 s_b[64 * 392];
    __shared__ float s_st[4][128];
    __shared__ int s_s[64], s_r[64];
    int tid = threadIdx.x;
    long long r0 = (long long)blockIdx.x * 64;
    if (tid < 128) {
        s_st[0][tid] = stats[S_M2_SC + tid];
        s_st[1][tid] = stats[S_M2_SC + 128 + tid];
        s_st[2][tid] = stats[S_M1_SC + tid];
        s_st[3][tid] = stats[S_M1_SC + 128 + tid];
    }
    if (tid < 64) {
        int r = (int)r0 + tid, b = r / EE, ed = r - b * EE;
        s_s[tid] = (b * NN + sidx[ed]) * 128;
        s_r[tid] = (b * NN + ridx[ed]) * 128;
    }
    __syncthreads();
    for (int i = tid; i < 8192; i += 256) {
        int row = i >> 7, j = i & 127;
        float sc2 = s_st[0][j], sh2 = s_st[1][j];
        s_b[row * 392 + j] = (_Float16)fmaf(xn[s_s[row] + j], sc2, sh2);
        s_b[row * 392 + 128 + j] = (_Float16)fmaf(xn[s_r[row] + j], sc2, sh2);
        s_b[row * 392 + 256 + j] = (_Float16)fmaf(bufB[(r0 + row) * 128 + j], s_st[2][j], s_st[3][j]);
    }
    __syncthreads();
    int w = tid >> 6, lane = tid & 63, quad = lane >> 4, l15 = lane & 15;
    f32x4 acc[2][4];
#pragma unroll
    for (int m = 0; m < 2; ++m)
#pragma unroll
        for (int nt = 0; nt < 4; ++nt) acc[m][nt] = (f32x4){0.f, 0.f, 0.f, 0.f};
    const f16x8* Ap = (const f16x8*)wp;
#pragma unroll
    for (int s = 0; s < 12; ++s) {
        f16x8 a0 = Ap[(s * 8 + 2 * w) * 64 + lane];
        f16x8 a1 = Ap[(s * 8 + 2 * w + 1) * 64 + lane];
#pragma unroll
        for (int nt = 0; nt < 4; ++nt) {
            f16x8 bfr = *(const f16x8*)((const char*)s_b + (nt * 16 + l15) * 784 + 64 * s + quad * 16);
            acc[0][nt] = __builtin_amdgcn_mfma_f32_16x16x32_f16(a0, bfr, acc[0][nt], 0, 0, 0);
            acc[1][nt] = __builtin_amdgcn_mfma_f32_16x16x32_f16(a1, bfr, acc[1][nt], 0, 0, 0);
        }
    }
#pragma unroll
    for (int m = 0; m < 2; ++m) {
        int j0 = (2 * w + m) * 16 + quad * 4;
        float4 bs = *(const float4*)(bias + j0);
#pragma unroll
        for (int nt = 0; nt < 4; ++nt) {
            int row = nt * 16 + l15;
            f16x4 o = {(_Float16)eluf(acc[m][nt][0] + bs.x),
                       (_Float16)eluf(acc[m][nt][1] + bs.y),
                       (_Float16)eluf(acc[m][nt][2] + bs.z),
                       (_Float16)eluf(acc[m][nt][3] + bs.w)};
            *(f16x4*)(out + (r0 + row) * 128 + j0) = o;
        }
    }
}

// ---------------- edge2node scatter-mean with inline BN-M1 ----------------
__global__ __launch_bounds__(128) void k_e2n(const float* __restrict__ bufB,
                                             const int* __restrict__ inc,
                                             const float* __restrict__ stats,
                                             float* __restrict__ xn) {
    int bn = blockIdx.x;
    int b = bn / NN, n = bn - b * NN;
    int j = threadIdx.x;
    float sc = stats[S_M1_SC + j], sh = stats[S_M1_SC + 128 + j];
    float s = 0.f;
    for (int k = 0; k < NN - 1; ++k) {
        int e = inc[n * (NN - 1) + k];
        s += bufB[(long long)(b * EE + e) * 128 + j];
    }
    xn[bn * 128 + j] = (s * sc + (float)(NN - 1) * sh) * (1.0f / (float)NN);
}

// ---------------- BN3 apply + fc_out (128 -> 16) ----------------
__global__ __launch_bounds__(256) void k_fcout(const float* __restrict__ h2,
                                               const float* __restrict__ stats,
                                               const float* __restrict__ fcw,
                                               const float* __restrict__ fcb,
                                               float* __restrict__ out) {
    __shared__ float s_x[16 * 129];
    __shared__ float s_w[16 * 129];
    int r0 = blockIdx.x * 16;
    int tid = threadIdx.x;
    for (int i = tid; i < 16 * 128; i += 256) {
        int rr = i >> 7, j = i & 127;
        s_x[rr * 129 + j] = fmaf(h2[(long long)(r0 + rr) * 128 + j],
                                 stats[S_M3_SC + j], stats[S_M3_SC + 128 + j]);
    }
    for (int i = tid; i < 16 * 128; i += 256) {
        int o = i >> 7, j = i & 127;
        s_w[o * 129 + j] = fcw[i];
    }
    __syncthreads();
    int rl = tid >> 4, o = tid & 15;
    float a = fcb[o];
    for (int j = 0; j < 128; ++j) a = fmaf(s_x[rl * 129 + j], s_w[o * 129 + j], a);
    out[(long long)(r0 + rl) * 16 + o] = a;
}

// ---------------- host launcher ----------------
extern "C" void kernel_launch(void* const* d_in, const int* in_sizes, int n_in,
                              void* d_out, int out_size, void* d_ws, size_t ws_size,
                              hipStream_t stream) {
    const float* inputs = (const float*)d_in[0];
    const float* rel_rec = (const float*)d_in[1];
    const float* rel_send = (const float*)d_in[2];
    const float* conv1_w = (const float*)d_in[3];
    const float* conv1_b = (const float*)d_in[4];
    const float* bn1_g = (const float*)d_in[5];
    const float* bn1_b = (const float*)d_in[6];
    const float* conv2_w = (const float*)d_in[7];
    const float* conv2_b = (const float*)d_in[8];
    const float* bn2_g = (const float*)d_in[9];
    const float* bn2_b = (const float*)d_in[10];
    const float* pred_w = (const float*)d_in[11];
    const float* pred_b = (const float*)d_in[12];
    const float* att_w = (const float*)d_in[13];
    const float* att_b = (const float*)d_in[14];
    const float* m1w1 = (const float*)d_in[15];
    const float* m1b1 = (const float*)d_in[16];
    const float* m1w2 = (const float*)d_in[17];
    const float* m1b2 = (const float*)d_in[18];
    const float* m1g = (const float*)d_in[19];
    const float* m1bb = (const float*)d_in[20];
    const float* m2w1 = (const float*)d_in[21];
    const float* m2b1 = (const float*)d_in[22];
    const float* m2w2 = (const float*)d_in[23];
    const float* m2b2 = (const float*)d_in[24];
    const float* m2g = (const float*)d_in[25];
    const float* m2bb = (const float*)d_in[26];
    const float* m3w1 = (const float*)d_in[27];
    const float* m3b1 = (const float*)d_in[28];
    const float* m3w2 = (const float*)d_in[29];
    const float* m3b2 = (const float*)d_in[30];
    const float* m3g = (const float*)d_in[31];
    const float* m3bb = (const float*)d_in[32];
    const float* fcw = (const float*)d_in[33];
    const float* fcb = (const float*)d_in[34];

    char* ws = (char*)d_ws;
    float* stats = (float*)(ws + OFF_STATS);
    int* sidx = (int*)(ws + OFF_SIDX);
    int* ridx = (int*)(ws + OFF_RIDX);
    int* inc = (int*)(ws + OFF_INC);
    _Float16* y23 = (_Float16*)(ws + OFF_Y23);
    float* x = (float*)(ws + OFF_X);
    float* bufB = (float*)(ws + OFF_BUFB);
    float* xn = (float*)(ws + OFF_XN);
    _Float16* apack = (_Float16*)(ws + OFF_APACK);
    _Float16* apack1 = (_Float16*)(ws + OFF_APACK1);
    float* pwt = (float*)(ws + OFF_PWT);
    float* w2sum = (float*)(ws + OFF_W2SUM);
    float* rep1 = (float*)(ws + OFF_REP1);
    float* rep2 = (float*)(ws + OFF_REP2);
    float* repm = (float*)(ws + OFF_REPM);
    _Float16* hf16 = (_Float16*)(ws + OFF_HF16);
    _Float16* mp = (_Float16*)(ws + OFF_MP);
    float* outp = (float*)d_out;

    hipLaunchKernelGGL(k_prep, dim3(125), dim3(256), 0, stream,
                       rel_rec, rel_send, conv2_w, conv1_w, pred_w,
                       m1w1, m1w2, m2w1, m2w2, m3w1, m3w2,
                       apack, apack1, pwt, w2sum, mp, rep1, rep2, repm, sidx, ridx, inc);
    hipLaunchKernelGGL(k_conv1_stats, dim3(BE), dim3(256), 0, stream,
                       inputs, apack1, conv1_b, sidx, ridx, rep1, y23);
    hipLaunchKernelGGL(k_finalize_bn1, dim3(1), dim3(128), 0, stream,
                       rep1, stats, bn1_g, bn1_b, w2sum, conv2_b, 1.0f / (float)(BE * L1));
    hipLaunchKernelGGL(k_scale, dim3(40), dim3(256), 0, stream, apack, stats);
    hipLaunchKernelGGL(k_conv2, dim3(BE), dim3(256), 0, stream,
                       y23, apack, stats, rep2);
    hipLaunchKernelGGL(k_finalize_rep, dim3(1), dim3(128), 0, stream,
                       rep2, stats, S_BN2_SC, bn2_g, bn2_b, 1.0f / (float)(BE * L2));
    hipLaunchKernelGGL(k_predatt, dim3(BE), dim3(256), 0, stream,
                       y23, stats, att_w, att_b, pwt, pred_b, x);
    // mlp1 (MFMA)
    hipLaunchKernelGGL((k_linmm<false, true, false>), dim3(BE / 64), dim3(256), 0, stream,
                       (const void*)x, mp + MP_M1W1, m1b1, (void*)hf16, repm);
    hipLaunchKernelGGL((k_linmm<true, false, true>), dim3(BE / 64), dim3(256), 0, stream,
                       (const void*)hf16, mp + MP_M1W2, m1b2, (void*)bufB, repm);
    hipLaunchKernelGGL(k_finalize_rep, dim3(1), dim3(128), 0, stream,
                       repm, stats, S_M1_SC, m1g, m1bb, 1.0f / (float)BE);
    // edge2node (BN-M1 inline) + mlp2 (MFMA)
    hipLaunchKernelGGL(k_e2n, dim3(BB * NN), dim3(128), 0, stream, bufB, inc, stats, xn);
    hipLaunchKernelGGL((k_linmm<false, true, false>), dim3(BB * NN / 64), dim3(256), 0, stream,
                       (const void*)xn, mp + MP_M2W1, m2b1, (void*)hf16, repm);
    hipLaunchKernelGGL((k_linmm<true, false, true>), dim3(BB * NN / 64), dim3(256), 0, stream,
                       (const void*)hf16, mp + MP_M2W2, m2b2, (void*)xn, repm);
    hipLaunchKernelGGL(k_finalize_rep, dim3(1), dim3(128), 0, stream,
                       repm, stats, S_M2_SC, m2g, m2bb, 1.0f / (float)(BB * NN));
    // node2edge + mlp3 (MFMA, gather + BN inline)
    hipLaunchKernelGGL(k_linmm3, dim3(BE / 64), dim3(256), 0, stream,
                       xn, bufB, sidx, ridx, stats, mp + MP_M3W1, m3b1, hf16);
    hipLaunchKernelGGL((k_linmm<true, false, true>), dim3(BE / 64), dim3(256), 0, stream,
                       (const void*)hf16, mp + MP_M3W2, m3b2, (void*)bufB, repm);
    hipLaunchKernelGGL(k_finalize_rep, dim3(1), dim3(128), 0, stream,
                       repm, stats, S_M3_SC, m3g, m3bb, 1.0f / (float)BE);
    // fc_out (BN-M3 inline)
    hipLaunchKernelGGL(k_fcout, dim3(BE / 16), dim3(256), 0, stream, bufB, stats, fcw, fcb, outp);
    (void)in_sizes; (void)n_in; (void)out_size; (void)ws_size;
}

// Round 16
// 594.708 us; speedup vs baseline: 1.0185x; 1.0185x over previous
//
#include <hip/hip_runtime.h>
#include <hip/hip_bf16.h>
#include <hip/hip_fp16.h>

// ---------------- problem constants ----------------
#define BB 32
#define NN 20
#define TT 100
#define DD 4
#define HH 128
#define EE 380          // N*(N-1)
#define BE 12160        // B*E
#define L1 96           // conv1 out length
#define LP 48           // after maxpool
#define L2 44           // conv2 out length
#define NOUT 16
#define EPS 1e-5f
#define NREP 64         // stats replicas (atomic de-contention)

typedef _Float16 f16x8 __attribute__((ext_vector_type(8)));
typedef _Float16 f16x4 __attribute__((ext_vector_type(4)));
typedef _Float16 f16x2 __attribute__((ext_vector_type(2)));
typedef float f32x4 __attribute__((ext_vector_type(4)));

// stats slot indices (floats): SC at base, SH at base+128. Slots 0..127 = conv2 bias2 (BN1-fold).
#define S_BIAS2 0
#define S_BN1_SC 256
#define S_BN2_SC 768
#define S_M1_SC 1280
#define S_M2_SC 1792
#define S_M3_SC 2304

// workspace offsets (bytes)
#define OFF_STATS 0ULL
#define OFF_SIDX 16384ULL
#define OFF_RIDX 18432ULL
#define OFF_INC 20480ULL
#define OFF_Y23 24576ULL                     // f16 [BE] slots of 6144: y2pre [48][128] then y3 t-major [44][128]
#define OFF_X 149446656ULL                   // f32 [BE][128]
#define OFF_BUFA 155672576ULL                // f32 [BE][128]; rep1/rep2 live here during conv phase
#define OFF_BUFB 161898496ULL                // f32 [BE][128]
#define OFF_XN 168124416ULL                  // f32 [640][128]
#define OFF_T640 168452096ULL                // conv-phase: apack(160K)+apack1(16K)+pwt(64K)+w2sum(64K)
#define OFF_REPM 168779776ULL                // f32 [64][256] MLP stats replicas
#define OFF_HF16 168845312ULL                // f16 [BE][128] MLP intermediates (3.1 MB)
#define OFF_MP 171958272ULL                  // f16 MLP weight packs (256 KB)
#define OFF_APACK OFF_T640
#define OFF_APACK1 (OFF_T640 + 163840ULL)
#define OFF_PWT (OFF_T640 + 180224ULL)
#define OFF_W2SUM (OFF_T640 + 245760ULL)
#define OFF_REP1 OFF_BUFA
#define OFF_REP2 (OFF_BUFA + 65536ULL)
// MP pack offsets in f16 units
#define MP_M1W1 0
#define MP_M1W2 16384
#define MP_M2W1 32768
#define MP_M2W2 49152
#define MP_M3W2 65536
#define MP_M3W1 81920

__device__ __forceinline__ float eluf(float v) { return v > 0.f ? v : expm1f(v); }

// ---------------- K prep: pack all MFMA weights, transpose pred_w, w2 tap-sums, init tables ----------------
// conv1 A-pack K-order c' = k*8 + ci (direct-from-time-major B, no im2col).
__global__ __launch_bounds__(256) void k_prep(const float* __restrict__ rel_rec,
                                              const float* __restrict__ rel_send,
                                              const float* __restrict__ w2,
                                              const float* __restrict__ w1,
                                              const float* __restrict__ pred_w,
                                              const float* __restrict__ m1w1,
                                              const float* __restrict__ m1w2,
                                              const float* __restrict__ m2w1,
                                              const float* __restrict__ m2w2,
                                              const float* __restrict__ m3w1,
                                              const float* __restrict__ m3w2,
                                              _Float16* __restrict__ apack,
                                              _Float16* __restrict__ apack1,
                                              float* __restrict__ pwt,
                                              float* __restrict__ w2sum,
                                              _Float16* __restrict__ mp,
                                              float* rep1, float* rep2, float* repm,
                                              int* sidx, int* ridx, int* inc) {
    int b = blockIdx.x;
    int tid = threadIdx.x;
    int l = tid & 63;
    if (b < 40) {            // conv2_w frags (raw; BN1 scale applied later by k_scale)
        int f = b * 4 + (tid >> 6);
        int m0 = f & 7, ks = f >> 3, s = ks & 3, k = ks >> 2;
        int m = m0 * 16 + (l & 15);
        int cbase = 32 * s + (l >> 4) * 8;
#pragma unroll
        for (int j = 0; j < 8; ++j)
            apack[(f * 64 + l) * 8 + j] = (_Float16)w2[m * 640 + (cbase + j) * 5 + k];
    } else if (b < 44) {     // conv1_w frags: c' = k*8+ci, taps k>=5 zero-padded
        int f = (b - 40) * 4 + (tid >> 6);
        int m0 = f & 7, s = f >> 3;
        int m = m0 * 16 + (l & 15);
        int cbase = 32 * s + (l >> 4) * 8;
#pragma unroll
        for (int j = 0; j < 8; ++j) {
            int c = cbase + j;
            int k = c >> 3, ci = c & 7;
            apack1[(f * 64 + l) * 8 + j] = (k < 5) ? (_Float16)w1[m * 40 + ci * 5 + k]
                                                   : (_Float16)0.f;
        }
    } else if (b == 44) {    // init: zero replicas, build edge tables
        for (int i = tid; i < NREP * 256; i += 256) { rep1[i] = 0.f; rep2[i] = 0.f; repm[i] = 0.f; }
        for (int e = tid; e < EE; e += 256) {
            int s = 0, r = 0;
            for (int n = 0; n < NN; ++n) {
                if (rel_send[e * NN + n] > 0.5f) s = n;
                if (rel_rec[e * NN + n] > 0.5f) r = n;
            }
            sidx[e] = s; ridx[e] = r;
        }
        __syncthreads();
        if (tid < NN) {
            int k = 0;
            for (int e = 0; e < EE; ++e)
                if (ridx[e] == tid) inc[tid * (NN - 1) + (k++)] = e;
        }
    } else if (b < 53) {     // transpose pred_w -> pwt[c][o]
        int idx = (b - 45) * 2048 + tid;
        for (int rep = 0; rep < 8; ++rep, idx += 256) {
            int o = idx >> 7, c = idx & 127;
            pwt[c * 128 + o] = pred_w[idx];
        }
    } else if (b < 117) {    // MLP weight packs: generic [128][K] -> A-frag-linear
        int idx = b - 53;    // 0..63
        const float* W; _Float16* dst; int K;
        if (idx < 8)       { W = m1w1; dst = mp + MP_M1W1; K = 128; }
        else if (idx < 16) { W = m1w2; dst = mp + MP_M1W2; K = 128; idx -= 8; }
        else if (idx < 24) { W = m2w1; dst = mp + MP_M2W1; K = 128; idx -= 16; }
        else if (idx < 32) { W = m2w2; dst = mp + MP_M2W2; K = 128; idx -= 24; }
        else if (idx < 40) { W = m3w2; dst = mp + MP_M3W2; K = 128; idx -= 32; }
        else               { W = m3w1; dst = mp + MP_M3W1; K = 384; idx -= 40; }
        int f = idx * 4 + (tid >> 6);
        int s = f >> 3, m0 = f & 7;
        int m = m0 * 16 + (l & 15);
        int cb = 32 * s + (l >> 4) * 8;
#pragma unroll
        for (int j = 0; j < 8; ++j)
            dst[(f * 64 + l) * 8 + j] = (_Float16)W[m * K + cb + j];
    } else {                 // w2 tap-sums: w2sum[co][ci] = sum_k w2[co][ci][k]
        int idx = (b - 117) * 2048 + tid;
        for (int rep = 0; rep < 8; ++rep, idx += 256) {
            const float* wr = w2 + idx * 5;
            w2sum[idx] = wr[0] + wr[1] + wr[2] + wr[3] + wr[4];
        }
    }
}

// ---------------- K1: conv1 (MFMA, direct-from-LDS B) + relu -> BN1 stats + PRE-BN maxpool ----------------
// pool-before-BN exact: bn1_g=1 -> BN scale>0 -> max commutes with fma.
__global__ __launch_bounds__(256) void k_conv1_stats(const float* __restrict__ inputs,
                                                     const _Float16* __restrict__ apack1,
                                                     const float* __restrict__ conv1_b,
                                                     const int* __restrict__ sidx,
                                                     const int* __restrict__ ridx,
                                                     float* rep1,
                                                     _Float16* __restrict__ y2p) {
    __shared__ __align__(16) _Float16 s_edgesT[104 * 8];
    __shared__ __align__(16) _Float16 s_y2t[48 * 136];
    int be = blockIdx.x;
    int b = be / EE, e = be - b * EE;
    int sn = sidx[e], rn = ridx[e];
    float* rep = rep1 + (be & (NREP - 1)) * 256;
    for (int i = threadIdx.x; i < 200; i += 256) {
        int side = (i >= 100) ? 1 : 0;
        int t = i - side * 100;
        int n = side ? rn : sn;
        float4 v = *(const float4*)(inputs + ((long long)(b * NN + n) * TT + t) * DD);
        f16x4 o = {(_Float16)v.x, (_Float16)v.y, (_Float16)v.z, (_Float16)v.w};
        *(f16x4*)(&s_edgesT[t * 8 + side * 4]) = o;
    }
    if (threadIdx.x < 32) s_edgesT[800 + threadIdx.x] = (_Float16)0.f;
    __syncthreads();
    int w = threadIdx.x >> 6, lane = threadIdx.x & 63;
    int quad = lane >> 4, l15 = lane & 15;
    f32x4 acc1[2][6];
#pragma unroll
    for (int m = 0; m < 2; ++m)
#pragma unroll
        for (int nt = 0; nt < 6; ++nt) acc1[m][nt] = (f32x4){0.f, 0.f, 0.f, 0.f};
    {
        const f16x8* Ap = (const f16x8*)apack1;
#pragma unroll
        for (int s = 0; s < 2; ++s) {
            f16x8 a0 = Ap[(s * 8 + 2 * w) * 64 + lane];
            f16x8 a1 = Ap[(s * 8 + 2 * w + 1) * 64 + lane];
#pragma unroll
            for (int nt = 0; nt < 6; ++nt) {
                f16x8 bfr = *(const f16x8*)(&s_edgesT[(nt * 16 + l15 + 4 * s + quad) * 8]);
                acc1[0][nt] = __builtin_amdgcn_mfma_f32_16x16x32_f16(a0, bfr, acc1[0][nt], 0, 0, 0);
                acc1[1][nt] = __builtin_amdgcn_mfma_f32_16x16x32_f16(a1, bfr, acc1[1][nt], 0, 0, 0);
            }
        }
    }
#pragma unroll
    for (int m = 0; m < 2; ++m) {
        int co0 = (2 * w + m) * 16 + quad * 4;
        float ss[4] = {0.f, 0.f, 0.f, 0.f}, qq[4] = {0.f, 0.f, 0.f, 0.f};
#pragma unroll
        for (int nt = 0; nt < 6; ++nt) {
            int t = nt * 16 + l15;
#pragma unroll
            for (int r = 0; r < 4; ++r) {
                float v = fmaxf(acc1[m][nt][r] + conv1_b[co0 + r], 0.f);
                ss[r] += v; qq[r] += v * v;
                float p = __shfl_xor(v, 1);
                if ((l15 & 1) == 0)
                    s_y2t[(t >> 1) * 136 + co0 + r] = (_Float16)fmaxf(v, p);
            }
        }
#pragma unroll
        for (int r = 0; r < 4; ++r) {
            float s = ss[r], q = qq[r];
            s += __shfl_xor(s, 1); s += __shfl_xor(s, 2); s += __shfl_xor(s, 4); s += __shfl_xor(s, 8);
            q += __shfl_xor(q, 1); q += __shfl_xor(q, 2); q += __shfl_xor(q, 4); q += __shfl_xor(q, 8);
            if (l15 == 0) {
                atomicAdd(&rep[co0 + r], s);
                atomicAdd(&rep[128 + co0 + r], q);
            }
        }
    }
    __syncthreads();
    _Float16* dst = y2p + (long long)be * 6144;
    for (int chunk = threadIdx.x; chunk < 768; chunk += 256) {
        int row = chunk >> 4, off = (chunk & 15) * 8;
        *(f16x8*)(dst + row * 128 + off) = *(const f16x8*)(&s_y2t[row * 136 + off]);
    }
}

// ---------------- finalize BN from 64 replicas -> scale/shift (re-zero replicas) ----------------
__global__ void k_finalize_rep(float* __restrict__ rep, float* stats, int scIdx,
                               const float* __restrict__ g, const float* __restrict__ bb,
                               float inv_count) {
    int j = threadIdx.x;
    float s = 0.f, q = 0.f;
    for (int i = 0; i < NREP; ++i) {
        s += rep[i * 256 + j];
        q += rep[i * 256 + 128 + j];
    }
    for (int i = 0; i < NREP; ++i) {
        rep[i * 256 + j] = 0.f;
        rep[i * 256 + 128 + j] = 0.f;
    }
    float m = s * inv_count;
    float v = fmaxf(q * inv_count - m * m, 0.f);
    float sc = g[j] * rsqrtf(v + EPS);
    stats[scIdx + j] = sc;
    stats[scIdx + 128 + j] = bb[j] - m * sc;
}

// ---------------- finalize BN1 + conv2 fused bias2[co] = conv2_b + sum_ci w2sum*sh ----------------
// Valid: every conv2 output t uses all 5 taps (VALID conv over 48 rows).
__global__ void k_finalize_bn1(float* __restrict__ rep, float* stats,
                               const float* __restrict__ g, const float* __restrict__ bb,
                               const float* __restrict__ w2sum, const float* __restrict__ conv2_b,
                               float inv_count) {
    __shared__ float s_sh[128];
    int j = threadIdx.x;  // 128
    float s = 0.f, q = 0.f;
    for (int i = 0; i < NREP; ++i) {
        s += rep[i * 256 + j];
        q += rep[i * 256 + 128 + j];
    }
    for (int i = 0; i < NREP; ++i) {
        rep[i * 256 + j] = 0.f;
        rep[i * 256 + 128 + j] = 0.f;
    }
    float m = s * inv_count;
    float v = fmaxf(q * inv_count - m * m, 0.f);
    float sc = g[j] * rsqrtf(v + EPS);
    float sh = bb[j] - m * sc;
    stats[S_BN1_SC + j] = sc;
    stats[S_BN1_SC + 128 + j] = sh;
    s_sh[j] = sh;
    __syncthreads();
    float acc = conv2_b[j];
    for (int ci = 0; ci < 128; ++ci)
        acc = fmaf(w2sum[j * 128 + ci], s_sh[ci], acc);
    stats[S_BIAS2 + j] = acc;
}

// ---------------- K scale: apack *= BN1 scale (per input channel), in place ----------------
// Deterministic per call: k_prep rewrites apack raw before this every launch.
__global__ __launch_bounds__(256) void k_scale(_Float16* __restrict__ apack,
                                               const float* __restrict__ stats) {
    int tid = threadIdx.x, l = tid & 63;
    int f = blockIdx.x * 4 + (tid >> 6);
    int s = (f >> 3) & 3;
    int cbase = 32 * s + (l >> 4) * 8;
    _Float16* p = apack + (f * 64 + l) * 8;
#pragma unroll
    for (int j = 0; j < 8; ++j)
        p[j] = (_Float16)((float)p[j] * stats[S_BN1_SC + cbase + j]);
}

// ---------------- K3: 2 edges/block (best measured: 148us); raw y2pre -> LDS (pure copy),
// conv2 MFMA (BN1 folded in A) -> y3 t-major [44][128] + BN2 stats.
// [LDS staging is load-bearing: LDS-free variant regressed 148->276 us (L1 thrash).]
// [2-edge > 1-edge: second edge-wave's A-frags hit L1 -> halves L2 A-traffic. 4-edge loses
//  to the LDS-occupancy cliff. This tile shape is the measured optimum.] ----------------
__global__ __launch_bounds__(256) void k_conv2(_Float16* __restrict__ y23,
                                               const _Float16* __restrict__ apack,
                                               const float* __restrict__ stats,
                                               float* rep2) {
    __shared__ __align__(16) _Float16 s_y2t[2][52 * 136];
    int tid = threadIdx.x;
    int be0 = blockIdx.x * 2;
    for (int i = tid; i < 544; i += 256) {
        int ed = i / 272, rem = i - ed * 272;
        ((int*)(&s_y2t[ed][48 * 136]))[rem] = 0;
    }
    for (int i = tid; i < 1536; i += 256) {
        int ed = i / 768, rem = i - ed * 768;
        int row = rem >> 4, c0 = (rem & 15) * 8;
        *(f16x8*)(&s_y2t[ed][row * 136 + c0]) =
            *(const f16x8*)(y23 + (long long)(be0 + ed) * 6144 + rem * 8);
    }
    __syncthreads();
    int w = tid >> 6, lane = tid & 63;
    int quad = lane >> 4, l15 = lane & 15;
    int g = w & 1, e = w >> 1;
    f32x4 acc[4][3];
#pragma unroll
    for (int m = 0; m < 4; ++m)
#pragma unroll
        for (int nt = 0; nt < 3; ++nt) acc[m][nt] = (f32x4){0.f, 0.f, 0.f, 0.f};
    const f16x8* Ap = (const f16x8*)apack;
    const char* base = (const char*)&s_y2t[e][0];
#pragma unroll
    for (int k = 0; k < 5; ++k) {
#pragma unroll
        for (int s = 0; s < 4; ++s) {
            f16x8 am[4];
#pragma unroll
            for (int m = 0; m < 4; ++m)
                am[m] = Ap[((k * 4 + s) * 8 + g * 4 + m) * 64 + lane];
#pragma unroll
            for (int nt = 0; nt < 3; ++nt) {
                f16x8 bfr = *(const f16x8*)(base + (nt * 16 + l15 + k) * 272 + 64 * s + quad * 16);
#pragma unroll
                for (int m = 0; m < 4; ++m)
                    acc[m][nt] = __builtin_amdgcn_mfma_f32_16x16x32_f16(am[m], bfr, acc[m][nt], 0, 0, 0);
            }
        }
    }
    // epilogue: bias2 + relu, store y3 t-major [44][128] (f16x4), BN2 stats
    int be = be0 + e;
    _Float16* y3 = y23 + (long long)be * 6144;
    float* rep = rep2 + (be & (NREP - 1)) * 256;
#pragma unroll
    for (int m = 0; m < 4; ++m) {
        int co0 = (g * 4 + m) * 16 + quad * 4;
        float4 bs = *(const float4*)(stats + S_BIAS2 + co0);
        float ssum[4] = {0.f, 0.f, 0.f, 0.f}, qsum[4] = {0.f, 0.f, 0.f, 0.f};
#pragma unroll
        for (int nt = 0; nt < 3; ++nt) {
            int t = nt * 16 + l15;
            if (t < 44) {
                float v0 = fmaxf(acc[m][nt][0] + bs.x, 0.f);
                float v1 = fmaxf(acc[m][nt][1] + bs.y, 0.f);
                float v2 = fmaxf(acc[m][nt][2] + bs.z, 0.f);
                float v3 = fmaxf(acc[m][nt][3] + bs.w, 0.f);
                f16x4 o = {(_Float16)v0, (_Float16)v1, (_Float16)v2, (_Float16)v3};
                *(f16x4*)(y3 + t * 128 + co0) = o;
                ssum[0] += v0; qsum[0] += v0 * v0;
                ssum[1] += v1; qsum[1] += v1 * v1;
                ssum[2] += v2; qsum[2] += v2 * v2;
                ssum[3] += v3; qsum[3] += v3 * v3;
            }
        }
#pragma unroll
        for (int r = 0; r < 4; ++r) {
            float s = ssum[r], q = qsum[r];
            s += __shfl_xor(s, 1); s += __shfl_xor(s, 2); s += __shfl_xor(s, 4); s += __shfl_xor(s, 8);
            q += __shfl_xor(q, 1); q += __shfl_xor(q, 2); q += __shfl_xor(q, 4); q += __shfl_xor(q, 8);
            if (l15 == 0) {
                atomicAdd(&rep[co0 + r], s);
                atomicAdd(&rep[128 + co0 + r], q);
            }
        }
    }
}

// ---------------- K5: BN2 apply + attention-pool -> x [BE][128] (y3 t-major input) ----------------
__global__ __launch_bounds__(256) void k_predatt(const _Float16* __restrict__ y23,
                                                 const float* __restrict__ stats,
                                                 const float* __restrict__ att_w,
                                                 const float* __restrict__ att_b,
                                                 const float* __restrict__ pwt,
                                                 const float* __restrict__ pred_b,
                                                 float* __restrict__ x) {
    __shared__ float h[44 * 132];   // h[t][c], stride 132 (pad 4)
    __shared__ float s_att[48];
    __shared__ float s_p1[256];
    __shared__ float s_p2[256];
    __shared__ float s_sc[128], s_sh[128];
    int be = blockIdx.x, tid = threadIdx.x;
    if (tid < 128) {
        s_sc[tid] = stats[S_BN2_SC + tid];
        s_sh[tid] = stats[S_BN2_SC + 128 + tid];
    }
    __syncthreads();
    const _Float16* yp = y23 + (long long)be * 6144;
    for (int i = tid; i < 704; i += 256) {   // 44 rows x 16 chunks of 8
        int t = i >> 4, c0 = (i & 15) * 8;
        f16x8 v = *(const f16x8*)(yp + i * 8);
        float4 a, bq;
        a.x = fmaf((float)v[0], s_sc[c0 + 0], s_sh[c0 + 0]);
        a.y = fmaf((float)v[1], s_sc[c0 + 1], s_sh[c0 + 1]);
        a.z = fmaf((float)v[2], s_sc[c0 + 2], s_sh[c0 + 2]);
        a.w = fmaf((float)v[3], s_sc[c0 + 3], s_sh[c0 + 3]);
        bq.x = fmaf((float)v[4], s_sc[c0 + 4], s_sh[c0 + 4]);
        bq.y = fmaf((float)v[5], s_sc[c0 + 5], s_sh[c0 + 5]);
        bq.z = fmaf((float)v[6], s_sc[c0 + 6], s_sh[c0 + 6]);
        bq.w = fmaf((float)v[7], s_sc[c0 + 7], s_sh[c0 + 7]);
        *(float4*)(&h[t * 132 + c0]) = a;
        *(float4*)(&h[t * 132 + c0 + 4]) = bq;
    }
    __syncthreads();
    int w = tid >> 6, lane = tid & 63;
    {
        float aw0 = att_w[lane], aw1 = att_w[64 + lane];
        for (int tt = 0; tt < 11; ++tt) {
            int t = w * 11 + tt;
            float p = h[t * 132 + lane] * aw0 + h[t * 132 + 64 + lane] * aw1;
            p += __shfl_xor(p, 1); p += __shfl_xor(p, 2); p += __shfl_xor(p, 4);
            p += __shfl_xor(p, 8); p += __shfl_xor(p, 16); p += __shfl_xor(p, 32);
            if (lane == 0) s_att[t] = p + att_b[0];
        }
    }
    __syncthreads();
    if (w == 0) {
        float v = (lane < 44) ? s_att[lane] : -1e30f;
        float m = v;
        m = fmaxf(m, __shfl_xor(m, 1)); m = fmaxf(m, __shfl_xor(m, 2));
        m = fmaxf(m, __shfl_xor(m, 4)); m = fmaxf(m, __shfl_xor(m, 8));
        m = fmaxf(m, __shfl_xor(m, 16)); m = fmaxf(m, __shfl_xor(m, 32));
        float ev = (lane < 44) ? expf(v - m) : 0.f;
        float ss = ev;
        ss += __shfl_xor(ss, 1); ss += __shfl_xor(ss, 2); ss += __shfl_xor(ss, 4);
        ss += __shfl_xor(ss, 8); ss += __shfl_xor(ss, 16); ss += __shfl_xor(ss, 32);
        if (lane < 44) s_att[lane] = ev / ss;
    }
    __syncthreads();
    {
        int c = tid & 127, hh = tid >> 7;
        float a = 0.f;
        for (int t = hh * 22; t < hh * 22 + 22; ++t) a = fmaf(h[t * 132 + c], s_att[t], a);
        s_p1[tid] = a;
    }
    __syncthreads();
    {
        int o = tid & 127, hh = tid >> 7;
        float a = 0.f;
        for (int c = hh * 64; c < hh * 64 + 64; ++c) {
            float hw = s_p1[c] + s_p1[128 + c];
            a = fmaf(pwt[c * 128 + o], hw, a);
        }
        s_p2[tid] = a;
    }
    __syncthreads();
    if (tid < 128) {
        float a = s_p2[tid] + s_p2[128 + tid] + pred_b[tid];
        x[(long long)be * 128 + tid] = a * (1.0f / 44.0f);
    }
}

// ---------------- MFMA linear (128 -> 128), 64 rows/block ----------------
template <bool IN16, bool OUT16, bool STATS>
__global__ __launch_bounds__(256) void k_linmm(const void* __restrict__ inV,
                                               const _Float16* __restrict__ wp,
                                               const float* __restrict__ bias,
                                               void* __restrict__ outV,
                                               float* __restrict__ repm) {
    __shared__ __align__(16) _Float16 s_b[64 * 136];
    int tid = threadIdx.x;
    long long r0 = (long long)blockIdx.x * 64;
    if (IN16) {
        const f16x8* src = (const f16x8*)((const _Float16*)inV + r0 * 128);
        for (int i = tid; i < 1024; i += 256) {
            int row = i >> 4, c0 = (i & 15) * 8;
            *(f16x8*)(&s_b[row * 136 + c0]) = src[i];
        }
    } else {
        const float4* src = (const float4*)((const float*)inV + r0 * 128);
        for (int i = tid; i < 2048; i += 256) {
            int row = i >> 5, c0 = (i & 31) * 4;
            float4 v = src[i];
            f16x4 o = {(_Float16)v.x, (_Float16)v.y, (_Float16)v.z, (_Float16)v.w};
            *(f16x4*)(&s_b[row * 136 + c0]) = o;
        }
    }
    __syncthreads();
    int w = tid >> 6, lane = tid & 63, quad = lane >> 4, l15 = lane & 15;
    f32x4 acc[2][4];
#pragma unroll
    for (int m = 0; m < 2; ++m)
#pragma unroll
        for (int nt = 0; nt < 4; ++nt) acc[m][nt] = (f32x4){0.f, 0.f, 0.f, 0.f};
    const f16x8* Ap = (const f16x8*)wp;
#pragma unroll
    for (int s = 0; s < 4; ++s) {
        f16x8 a0 = Ap[(s * 8 + 2 * w) * 64 + lane];
        f16x8 a1 = Ap[(s * 8 + 2 * w + 1) * 64 + lane];
#pragma unroll
        for (int nt = 0; nt < 4; ++nt) {
            f16x8 bfr = *(const f16x8*)((const char*)s_b + (nt * 16 + l15) * 272 + 64 * s + quad * 16);
            acc[0][nt] = __builtin_amdgcn_mfma_f32_16x16x32_f16(a0, bfr, acc[0][nt], 0, 0, 0);
            acc[1][nt] = __builtin_amdgcn_mfma_f32_16x16x32_f16(a1, bfr, acc[1][nt], 0, 0, 0);
        }
    }
#pragma unroll
    for (int m = 0; m < 2; ++m) {
        int j0 = (2 * w + m) * 16 + quad * 4;
        float4 bs = *(const float4*)(bias + j0);
        float ss[4] = {0.f, 0.f, 0.f, 0.f}, qq[4] = {0.f, 0.f, 0.f, 0.f};
#pragma unroll
        for (int nt = 0; nt < 4; ++nt) {
            int row = nt * 16 + l15;
            float v0 = eluf(acc[m][nt][0] + bs.x);
            float v1 = eluf(acc[m][nt][1] + bs.y);
            float v2 = eluf(acc[m][nt][2] + bs.z);
            float v3 = eluf(acc[m][nt][3] + bs.w);
            if (OUT16) {
                f16x4 o = {(_Float16)v0, (_Float16)v1, (_Float16)v2, (_Float16)v3};
                *(f16x4*)((_Float16*)outV + (r0 + row) * 128 + j0) = o;
            } else {
                float4 o = {v0, v1, v2, v3};
                *(float4*)((float*)outV + (r0 + row) * 128 + j0) = o;
            }
            if (STATS) {
                ss[0] += v0; qq[0] += v0 * v0;
                ss[1] += v1; qq[1] += v1 * v1;
                ss[2] += v2; qq[2] += v2 * v2;
                ss[3] += v3; qq[3] += v3 * v3;
            }
        }
        if (STATS) {
            float* rep = repm + (blockIdx.x & (NREP - 1)) * 256;
#pragma unroll
            for (int r = 0; r < 4; ++r) {
                float s = ss[r], q = qq[r];
                s += __shfl_xor(s, 1); s += __shfl_xor(s, 2); s += __shfl_xor(s, 4); s += __shfl_xor(s, 8);
                q += __shfl_xor(q, 1); q += __shfl_xor(q, 2); q += __shfl_xor(q, 4); q += __shfl_xor(q, 8);
                if (l15 == 0) {
                    atomicAdd(&rep[j0 + r], s);
                    atomicAdd(&rep[128 + j0 + r], q);
                }
            }
        }
    }
}

// ---------------- MFMA mlp3 l1: gather-concat [send|recv|skip] (K=384) -> 128 f16 ----------------
__global__ __launch_bounds__(256) void k_linmm3(const float* __restrict__ xn,
                                                const float* __restrict__ bufB,
                                                const int* __restrict__ sidx,
                                                const int* __restrict__ ridx,
                                                const float* __restrict__ stats,
                                                const _Float16* __restrict__ wp,
                                                const float* __restrict__ bias,
                                                _Float16* __restrict__ out) {
    __shared__ __align__(16) _Float16 s_b[64 * 392];
    __shared__ float s_st[4][128];
    __shared__ int s_s[64], s_r[64];
    int tid = threadIdx.x;
    long long r0 = (long long)blockIdx.x * 64;
    if (tid < 128) {
        s_st[0][tid] = stats[S_M2_SC + tid];
        s_st[1][tid] = stats[S_M2_SC + 128 + tid];
        s_st[2][tid] = stats[S_M1_SC + tid];
        s_st[3][tid] = stats[S_M1_SC + 128 + tid];
    }
    if (tid < 64) {
        int r = (int)r0 + tid, b = r / EE, ed = r - b * EE;
        s_s[tid] = (b * NN + sidx[ed]) * 128;
        s_r[tid] = (b * NN + ridx[ed]) * 128;
    }
    __syncthreads();
    for (int i = tid; i < 8192; i += 256) {
        int row = i >> 7, j = i & 127;
        float sc2 = s_st[0][j], sh2 = s_st[1][j];
        s_b[row * 392 + j] = (_Float16)fmaf(xn[s_s[row] + j], sc2, sh2);
        s_b[row * 392 + 128 + j] = (_Float16)fmaf(xn[s_r[row] + j], sc2, sh2);
        s_b[row * 392 + 256 + j] = (_Float16)fmaf(bufB[(r0 + row) * 128 + j], s_st[2][j], s_st[3][j]);
    }
    __syncthreads();
    int w = tid >> 6, lane = tid & 63, quad = lane >> 4, l15 = lane & 15;
    f32x4 acc[2][4];
#pragma unroll
    for (int m = 0; m < 2; ++m)
#pragma unroll
        for (int nt = 0; nt < 4; ++nt) acc[m][nt] = (f32x4){0.f, 0.f, 0.f, 0.f};
    const f16x8* Ap = (const f16x8*)wp;
#pragma unroll
    for (int s = 0; s < 12; ++s) {
        f16x8 a0 = Ap[(s * 8 + 2 * w) * 64 + lane];
        f16x8 a1 = Ap[(s * 8 + 2 * w + 1) * 64 + lane];
#pragma unroll
        for (int nt = 0; nt < 4; ++nt) {
            f16x8 bfr = *(const f16x8*)((const char*)s_b + (nt * 16 + l15) * 784 + 64 * s + quad * 16);
            acc[0][nt] = __builtin_amdgcn_mfma_f32_16x16x32_f16(a0, bfr, acc[0][nt], 0, 0, 0);
            acc[1][nt] = __builtin_amdgcn_mfma_f32_16x16x32_f16(a1, bfr, acc[1][nt], 0, 0, 0);
        }
    }
#pragma unroll
    for (int m = 0; m < 2; ++m) {
        int j0 = (2 * w + m) * 16 + quad * 4;
        float4 bs = *(const float4*)(bias + j0);
#pragma unroll
        for (int nt = 0; nt < 4; ++nt) {
            int row = nt * 16 + l15;
            f16x4 o = {(_Float16)eluf(acc[m][nt][0] + bs.x),
                       (_Float16)eluf(acc[m][nt][1] + bs.y),
                       (_Float16)eluf(acc[m][nt][2] + bs.z),
                       (_Float16)eluf(acc[m][nt][3] + bs.w)};
            *(f16x4*)(out + (r0 + row) * 128 + j0) = o;
        }
    }
}

// ---------------- edge2node scatter-mean with inline BN-M1 ----------------
__global__ __launch_bounds__(128) void k_e2n(const float* __restrict__ bufB,
                                             const int* __restrict__ inc,
                                             const float* __restrict__ stats,
                                             float* __restrict__ xn) {
    int bn = blockIdx.x;
    int b = bn / NN, n = bn - b * NN;
    int j = threadIdx.x;
    float sc = stats[S_M1_SC + j], sh = stats[S_M1_SC + 128 + j];
    float s = 0.f;
    for (int k = 0; k < NN - 1; ++k) {
        int e = inc[n * (NN - 1) + k];
        s += bufB[(long long)(b * EE + e) * 128 + j];
    }
    xn[bn * 128 + j] = (s * sc + (float)(NN - 1) * sh) * (1.0f / (float)NN);
}

// ---------------- BN3 apply + fc_out (128 -> 16) ----------------
__global__ __launch_bounds__(256) void k_fcout(const float* __restrict__ h2,
                                               const float* __restrict__ stats,
                                               const float* __restrict__ fcw,
                                               const float* __restrict__ fcb,
                                               float* __restrict__ out) {
    __shared__ float s_x[16 * 129];
    __shared__ float s_w[16 * 129];
    int r0 = blockIdx.x * 16;
    int tid = threadIdx.x;
    for (int i = tid; i < 16 * 128; i += 256) {
        int rr = i >> 7, j = i & 127;
        s_x[rr * 129 + j] = fmaf(h2[(long long)(r0 + rr) * 128 + j],
                                 stats[S_M3_SC + j], stats[S_M3_SC + 128 + j]);
    }
    for (int i = tid; i < 16 * 128; i += 256) {
        int o = i >> 7, j = i & 127;
        s_w[o * 129 + j] = fcw[i];
    }
    __syncthreads();
    int rl = tid >> 4, o = tid & 15;
    float a = fcb[o];
    for (int j = 0; j < 128; ++j) a = fmaf(s_x[rl * 129 + j], s_w[o * 129 + j], a);
    out[(long long)(r0 + rl) * 16 + o] = a;
}

// ---------------- host launcher ----------------
extern "C" void kernel_launch(void* const* d_in, const int* in_sizes, int n_in,
                              void* d_out, int out_size, void* d_ws, size_t ws_size,
                              hipStream_t stream) {
    const float* inputs = (const float*)d_in[0];
    const float* rel_rec = (const float*)d_in[1];
    const float* rel_send = (const float*)d_in[2];
    const float* conv1_w = (const float*)d_in[3];
    const float* conv1_b = (const float*)d_in[4];
    const float* bn1_g = (const float*)d_in[5];
    const float* bn1_b = (const float*)d_in[6];
    const float* conv2_w = (const float*)d_in[7];
    const float* conv2_b = (const float*)d_in[8];
    const float* bn2_g = (const float*)d_in[9];
    const float* bn2_b = (const float*)d_in[10];
    const float* pred_w = (const float*)d_in[11];
    const float* pred_b = (const float*)d_in[12];
    const float* att_w = (const float*)d_in[13];
    const float* att_b = (const float*)d_in[14];
    const float* m1w1 = (const float*)d_in[15];
    const float* m1b1 = (const float*)d_in[16];
    const float* m1w2 = (const float*)d_in[17];
    const float* m1b2 = (const float*)d_in[18];
    const float* m1g = (const float*)d_in[19];
    const float* m1bb = (const float*)d_in[20];
    const float* m2w1 = (const float*)d_in[21];
    const float* m2b1 = (const float*)d_in[22];
    const float* m2w2 = (const float*)d_in[23];
    const float* m2b2 = (const float*)d_in[24];
    const float* m2g = (const float*)d_in[25];
    const float* m2bb = (const float*)d_in[26];
    const float* m3w1 = (const float*)d_in[27];
    const float* m3b1 = (const float*)d_in[28];
    const float* m3w2 = (const float*)d_in[29];
    const float* m3b2 = (const float*)d_in[30];
    const float* m3g = (const float*)d_in[31];
    const float* m3bb = (const float*)d_in[32];
    const float* fcw = (const float*)d_in[33];
    const float* fcb = (const float*)d_in[34];

    char* ws = (char*)d_ws;
    float* stats = (float*)(ws + OFF_STATS);
    int* sidx = (int*)(ws + OFF_SIDX);
    int* ridx = (int*)(ws + OFF_RIDX);
    int* inc = (int*)(ws + OFF_INC);
    _Float16* y23 = (_Float16*)(ws + OFF_Y23);
    float* x = (float*)(ws + OFF_X);
    float* bufB = (float*)(ws + OFF_BUFB);
    float* xn = (float*)(ws + OFF_XN);
    _Float16* apack = (_Float16*)(ws + OFF_APACK);
    _Float16* apack1 = (_Float16*)(ws + OFF_APACK1);
    float* pwt = (float*)(ws + OFF_PWT);
    float* w2sum = (float*)(ws + OFF_W2SUM);
    float* rep1 = (float*)(ws + OFF_REP1);
    float* rep2 = (float*)(ws + OFF_REP2);
    float* repm = (float*)(ws + OFF_REPM);
    _Float16* hf16 = (_Float16*)(ws + OFF_HF16);
    _Float16* mp = (_Float16*)(ws + OFF_MP);
    float* outp = (float*)d_out;

    hipLaunchKernelGGL(k_prep, dim3(125), dim3(256), 0, stream,
                       rel_rec, rel_send, conv2_w, conv1_w, pred_w,
                       m1w1, m1w2, m2w1, m2w2, m3w1, m3w2,
                       apack, apack1, pwt, w2sum, mp, rep1, rep2, repm, sidx, ridx, inc);
    hipLaunchKernelGGL(k_conv1_stats, dim3(BE), dim3(256), 0, stream,
                       inputs, apack1, conv1_b, sidx, ridx, rep1, y23);
    hipLaunchKernelGGL(k_finalize_bn1, dim3(1), dim3(128), 0, stream,
                       rep1, stats, bn1_g, bn1_b, w2sum, conv2_b, 1.0f / (float)(BE * L1));
    hipLaunchKernelGGL(k_scale, dim3(40), dim3(256), 0, stream, apack, stats);
    hipLaunchKernelGGL(k_conv2, dim3(BE / 2), dim3(256), 0, stream,
                       y23, apack, stats, rep2);
    hipLaunchKernelGGL(k_finalize_rep, dim3(1), dim3(128), 0, stream,
                       rep2, stats, S_BN2_SC, bn2_g, bn2_b, 1.0f / (float)(BE * L2));
    hipLaunchKernelGGL(k_predatt, dim3(BE), dim3(256), 0, stream,
                       y23, stats, att_w, att_b, pwt, pred_b, x);
    // mlp1 (MFMA)
    hipLaunchKernelGGL((k_linmm<false, true, false>), dim3(BE / 64), dim3(256), 0, stream,
                       (const void*)x, mp + MP_M1W1, m1b1, (void*)hf16, repm);
    hipLaunchKernelGGL((k_linmm<true, false, true>), dim3(BE / 64), dim3(256), 0, stream,
                       (const void*)hf16, mp + MP_M1W2, m1b2, (void*)bufB, repm);
    hipLaunchKernelGGL(k_finalize_rep, dim3(1), dim3(128), 0, stream,
                       repm, stats, S_M1_SC, m1g, m1bb, 1.0f / (float)BE);
    // edge2node (BN-M1 inline) + mlp2 (MFMA)
    hipLaunchKernelGGL(k_e2n, dim3(BB * NN), dim3(128), 0, stream, bufB, inc, stats, xn);
    hipLaunchKernelGGL((k_linmm<false, true, false>), dim3(BB * NN / 64), dim3(256), 0, stream,
                       (const void*)xn, mp + MP_M2W1, m2b1, (void*)hf16, repm);
    hipLaunchKernelGGL((k_linmm<true, false, true>), dim3(BB * NN / 64), dim3(256), 0, stream,
                       (const void*)hf16, mp + MP_M2W2, m2b2, (void*)xn, repm);
    hipLaunchKernelGGL(k_finalize_rep, dim3(1), dim3(128), 0, stream,
                       repm, stats, S_M2_SC, m2g, m2bb, 1.0f / (float)(BB * NN));
    // node2edge + mlp3 (MFMA, gather + BN inline)
    hipLaunchKernelGGL(k_linmm3, dim3(BE / 64), dim3(256), 0, stream,
                       xn, bufB, sidx, ridx, stats, mp + MP_M3W1, m3b1, hf16);
    hipLaunchKernelGGL((k_linmm<true, false, true>), dim3(BE / 64), dim3(256), 0, stream,
                       (const void*)hf16, mp + MP_M3W2, m3b2, (void*)bufB, repm);
    hipLaunchKernelGGL(k_finalize_rep, dim3(1), dim3(128), 0, stream,
                       repm, stats, S_M3_SC, m3g, m3bb, 1.0f / (float)BE);
    // fc_out (BN-M3 inline)
    hipLaunchKernelGGL(k_fcout, dim3(BE / 16), dim3(256), 0, stream, bufB, stats, fcw, fcb, outp);
    (void)in_sizes; (void)n_in; (void)out_size; (void)ws_size;
}

// Round 17
// 582.323 us; speedup vs baseline: 1.0401x; 1.0213x over previous
//
#include <hip/hip_runtime.h>
#include <hip/hip_bf16.h>
#include <hip/hip_fp16.h>

// ---------------- problem constants ----------------
#define BB 32
#define NN 20
#define TT 100
#define DD 4
#define HH 128
#define EE 380          // N*(N-1)
#define BE 12160        // B*E
#define L1 96           // conv1 out length
#define LP 48           // after maxpool
#define L2 44           // conv2 out length
#define NOUT 16
#define EPS 1e-5f
#define NREP 64         // stats replicas (atomic de-contention)

typedef _Float16 f16x8 __attribute__((ext_vector_type(8)));
typedef _Float16 f16x4 __attribute__((ext_vector_type(4)));
typedef _Float16 f16x2 __attribute__((ext_vector_type(2)));
typedef float f32x4 __attribute__((ext_vector_type(4)));

// stats slot indices (floats): SC at base, SH at base+128. Slots 0..127 = conv2 bias2 (BN1-fold).
#define S_BIAS2 0
#define S_BN1_SC 256
#define S_BN2_SC 768
#define S_M1_SC 1280
#define S_M2_SC 1792
#define S_M3_SC 2304

// workspace offsets (bytes)
#define OFF_STATS 0ULL
#define OFF_SIDX 16384ULL
#define OFF_RIDX 18432ULL
#define OFF_INC 20480ULL
#define OFF_Y23 24576ULL                     // f16 [BE] slots of 6144: y2pre [48][128] then y3 t-major [44][128]
#define OFF_X 149446656ULL                   // f32 [BE][128]
#define OFF_BUFA 155672576ULL                // f32 [BE][128]; rep1/rep2 live here during conv phase
#define OFF_BUFB 161898496ULL                // f32 [BE][128]
#define OFF_XN 168124416ULL                  // f32 [640][128]
#define OFF_T640 168452096ULL                // conv-phase: apack(160K)+apack1(16K)+pwt(64K)+w2sum(64K)
#define OFF_REPM 168779776ULL                // f32 [64][256] MLP stats replicas
#define OFF_MP 171958272ULL                  // f16 MLP weight packs (256 KB)
#define OFF_APACK OFF_T640
#define OFF_APACK1 (OFF_T640 + 163840ULL)
#define OFF_PWT (OFF_T640 + 180224ULL)
#define OFF_W2SUM (OFF_T640 + 245760ULL)
#define OFF_REP1 OFF_BUFA
#define OFF_REP2 (OFF_BUFA + 65536ULL)
// MP pack offsets in f16 units
#define MP_M1W1 0
#define MP_M1W2 16384
#define MP_M2W1 32768
#define MP_M2W2 49152
#define MP_M3W2 65536
#define MP_M3W1 81920

__device__ __forceinline__ float eluf(float v) { return v > 0.f ? v : expm1f(v); }

// ---------------- K prep: pack all MFMA weights, transpose pred_w, w2 tap-sums, init tables ----------------
// conv1 A-pack K-order c' = k*8 + ci (direct-from-time-major B, no im2col).
__global__ __launch_bounds__(256) void k_prep(const float* __restrict__ rel_rec,
                                              const float* __restrict__ rel_send,
                                              const float* __restrict__ w2,
                                              const float* __restrict__ w1,
                                              const float* __restrict__ pred_w,
                                              const float* __restrict__ m1w1,
                                              const float* __restrict__ m1w2,
                                              const float* __restrict__ m2w1,
                                              const float* __restrict__ m2w2,
                                              const float* __restrict__ m3w1,
                                              const float* __restrict__ m3w2,
                                              _Float16* __restrict__ apack,
                                              _Float16* __restrict__ apack1,
                                              float* __restrict__ pwt,
                                              float* __restrict__ w2sum,
                                              _Float16* __restrict__ mp,
                                              float* rep1, float* rep2, float* repm,
                                              int* sidx, int* ridx, int* inc) {
    int b = blockIdx.x;
    int tid = threadIdx.x;
    int l = tid & 63;
    if (b < 40) {            // conv2_w frags (raw; BN1 scale applied later by k_scale)
        int f = b * 4 + (tid >> 6);
        int m0 = f & 7, ks = f >> 3, s = ks & 3, k = ks >> 2;
        int m = m0 * 16 + (l & 15);
        int cbase = 32 * s + (l >> 4) * 8;
#pragma unroll
        for (int j = 0; j < 8; ++j)
            apack[(f * 64 + l) * 8 + j] = (_Float16)w2[m * 640 + (cbase + j) * 5 + k];
    } else if (b < 44) {     // conv1_w frags: c' = k*8+ci, taps k>=5 zero-padded
        int f = (b - 40) * 4 + (tid >> 6);
        int m0 = f & 7, s = f >> 3;
        int m = m0 * 16 + (l & 15);
        int cbase = 32 * s + (l >> 4) * 8;
#pragma unroll
        for (int j = 0; j < 8; ++j) {
            int c = cbase + j;
            int k = c >> 3, ci = c & 7;
            apack1[(f * 64 + l) * 8 + j] = (k < 5) ? (_Float16)w1[m * 40 + ci * 5 + k]
                                                   : (_Float16)0.f;
        }
    } else if (b == 44) {    // init: zero replicas, build edge tables
        for (int i = tid; i < NREP * 256; i += 256) { rep1[i] = 0.f; rep2[i] = 0.f; repm[i] = 0.f; }
        for (int e = tid; e < EE; e += 256) {
            int s = 0, r = 0;
            for (int n = 0; n < NN; ++n) {
                if (rel_send[e * NN + n] > 0.5f) s = n;
                if (rel_rec[e * NN + n] > 0.5f) r = n;
            }
            sidx[e] = s; ridx[e] = r;
        }
        __syncthreads();
        if (tid < NN) {
            int k = 0;
            for (int e = 0; e < EE; ++e)
                if (ridx[e] == tid) inc[tid * (NN - 1) + (k++)] = e;
        }
    } else if (b < 53) {     // transpose pred_w -> pwt[c][o]
        int idx = (b - 45) * 2048 + tid;
        for (int rep = 0; rep < 8; ++rep, idx += 256) {
            int o = idx >> 7, c = idx & 127;
            pwt[c * 128 + o] = pred_w[idx];
        }
    } else if (b < 117) {    // MLP weight packs: generic [128][K] -> A-frag-linear
        int idx = b - 53;    // 0..63
        const float* W; _Float16* dst; int K;
        if (idx < 8)       { W = m1w1; dst = mp + MP_M1W1; K = 128; }
        else if (idx < 16) { W = m1w2; dst = mp + MP_M1W2; K = 128; idx -= 8; }
        else if (idx < 24) { W = m2w1; dst = mp + MP_M2W1; K = 128; idx -= 16; }
        else if (idx < 32) { W = m2w2; dst = mp + MP_M2W2; K = 128; idx -= 24; }
        else if (idx < 40) { W = m3w2; dst = mp + MP_M3W2; K = 128; idx -= 32; }
        else               { W = m3w1; dst = mp + MP_M3W1; K = 384; idx -= 40; }
        int f = idx * 4 + (tid >> 6);
        int s = f >> 3, m0 = f & 7;
        int m = m0 * 16 + (l & 15);
        int cb = 32 * s + (l >> 4) * 8;
#pragma unroll
        for (int j = 0; j < 8; ++j)
            dst[(f * 64 + l) * 8 + j] = (_Float16)W[m * K + cb + j];
    } else {                 // w2 tap-sums: w2sum[co][ci] = sum_k w2[co][ci][k]
        int idx = (b - 117) * 2048 + tid;
        for (int rep = 0; rep < 8; ++rep, idx += 256) {
            const float* wr = w2 + idx * 5;
            w2sum[idx] = wr[0] + wr[1] + wr[2] + wr[3] + wr[4];
        }
    }
}

// ---------------- K1: conv1 (MFMA, direct-from-LDS B) + relu -> BN1 stats + PRE-BN maxpool ----------------
// pool-before-BN exact: bn1_g=1 -> BN scale>0 -> max commutes with fma.
__global__ __launch_bounds__(256) void k_conv1_stats(const float* __restrict__ inputs,
                                                     const _Float16* __restrict__ apack1,
                                                     const float* __restrict__ conv1_b,
                                                     const int* __restrict__ sidx,
                                                     const int* __restrict__ ridx,
                                                     float* rep1,
                                                     _Float16* __restrict__ y2p) {
    __shared__ __align__(16) _Float16 s_edgesT[104 * 8];
    __shared__ __align__(16) _Float16 s_y2t[48 * 136];
    int be = blockIdx.x;
    int b = be / EE, e = be - b * EE;
    int sn = sidx[e], rn = ridx[e];
    float* rep = rep1 + (be & (NREP - 1)) * 256;
    for (int i = threadIdx.x; i < 200; i += 256) {
        int side = (i >= 100) ? 1 : 0;
        int t = i - side * 100;
        int n = side ? rn : sn;
        float4 v = *(const float4*)(inputs + ((long long)(b * NN + n) * TT + t) * DD);
        f16x4 o = {(_Float16)v.x, (_Float16)v.y, (_Float16)v.z, (_Float16)v.w};
        *(f16x4*)(&s_edgesT[t * 8 + side * 4]) = o;
    }
    if (threadIdx.x < 32) s_edgesT[800 + threadIdx.x] = (_Float16)0.f;
    __syncthreads();
    int w = threadIdx.x >> 6, lane = threadIdx.x & 63;
    int quad = lane >> 4, l15 = lane & 15;
    f32x4 acc1[2][6];
#pragma unroll
    for (int m = 0; m < 2; ++m)
#pragma unroll
        for (int nt = 0; nt < 6; ++nt) acc1[m][nt] = (f32x4){0.f, 0.f, 0.f, 0.f};
    {
        const f16x8* Ap = (const f16x8*)apack1;
#pragma unroll
        for (int s = 0; s < 2; ++s) {
            f16x8 a0 = Ap[(s * 8 + 2 * w) * 64 + lane];
            f16x8 a1 = Ap[(s * 8 + 2 * w + 1) * 64 + lane];
#pragma unroll
            for (int nt = 0; nt < 6; ++nt) {
                f16x8 bfr = *(const f16x8*)(&s_edgesT[(nt * 16 + l15 + 4 * s + quad) * 8]);
                acc1[0][nt] = __builtin_amdgcn_mfma_f32_16x16x32_f16(a0, bfr, acc1[0][nt], 0, 0, 0);
                acc1[1][nt] = __builtin_amdgcn_mfma_f32_16x16x32_f16(a1, bfr, acc1[1][nt], 0, 0, 0);
            }
        }
    }
#pragma unroll
    for (int m = 0; m < 2; ++m) {
        int co0 = (2 * w + m) * 16 + quad * 4;
        float ss[4] = {0.f, 0.f, 0.f, 0.f}, qq[4] = {0.f, 0.f, 0.f, 0.f};
#pragma unroll
        for (int nt = 0; nt < 6; ++nt) {
            int t = nt * 16 + l15;
#pragma unroll
            for (int r = 0; r < 4; ++r) {
                float v = fmaxf(acc1[m][nt][r] + conv1_b[co0 + r], 0.f);
                ss[r] += v; qq[r] += v * v;
                float p = __shfl_xor(v, 1);
                if ((l15 & 1) == 0)
                    s_y2t[(t >> 1) * 136 + co0 + r] = (_Float16)fmaxf(v, p);
            }
        }
#pragma unroll
        for (int r = 0; r < 4; ++r) {
            float s = ss[r], q = qq[r];
            s += __shfl_xor(s, 1); s += __shfl_xor(s, 2); s += __shfl_xor(s, 4); s += __shfl_xor(s, 8);
            q += __shfl_xor(q, 1); q += __shfl_xor(q, 2); q += __shfl_xor(q, 4); q += __shfl_xor(q, 8);
            if (l15 == 0) {
                atomicAdd(&rep[co0 + r], s);
                atomicAdd(&rep[128 + co0 + r], q);
            }
        }
    }
    __syncthreads();
    _Float16* dst = y2p + (long long)be * 6144;
    for (int chunk = threadIdx.x; chunk < 768; chunk += 256) {
        int row = chunk >> 4, off = (chunk & 15) * 8;
        *(f16x8*)(dst + row * 128 + off) = *(const f16x8*)(&s_y2t[row * 136 + off]);
    }
}

// ---------------- finalize BN from 64 replicas -> scale/shift (re-zero replicas) ----------------
__global__ void k_finalize_rep(float* __restrict__ rep, float* stats, int scIdx,
                               const float* __restrict__ g, const float* __restrict__ bb,
                               float inv_count) {
    int j = threadIdx.x;
    float s = 0.f, q = 0.f;
    for (int i = 0; i < NREP; ++i) {
        s += rep[i * 256 + j];
        q += rep[i * 256 + 128 + j];
    }
    for (int i = 0; i < NREP; ++i) {
        rep[i * 256 + j] = 0.f;
        rep[i * 256 + 128 + j] = 0.f;
    }
    float m = s * inv_count;
    float v = fmaxf(q * inv_count - m * m, 0.f);
    float sc = g[j] * rsqrtf(v + EPS);
    stats[scIdx + j] = sc;
    stats[scIdx + 128 + j] = bb[j] - m * sc;
}

// ---------------- finalize BN1 + conv2 fused bias2[co] = conv2_b + sum_ci w2sum*sh ----------------
// Valid: every conv2 output t uses all 5 taps (VALID conv over 48 rows).
__global__ void k_finalize_bn1(float* __restrict__ rep, float* stats,
                               const float* __restrict__ g, const float* __restrict__ bb,
                               const float* __restrict__ w2sum, const float* __restrict__ conv2_b,
                               float inv_count) {
    __shared__ float s_sh[128];
    int j = threadIdx.x;  // 128
    float s = 0.f, q = 0.f;
    for (int i = 0; i < NREP; ++i) {
        s += rep[i * 256 + j];
        q += rep[i * 256 + 128 + j];
    }
    for (int i = 0; i < NREP; ++i) {
        rep[i * 256 + j] = 0.f;
        rep[i * 256 + 128 + j] = 0.f;
    }
    float m = s * inv_count;
    float v = fmaxf(q * inv_count - m * m, 0.f);
    float sc = g[j] * rsqrtf(v + EPS);
    float sh = bb[j] - m * sc;
    stats[S_BN1_SC + j] = sc;
    stats[S_BN1_SC + 128 + j] = sh;
    s_sh[j] = sh;
    __syncthreads();
    float acc = conv2_b[j];
    for (int ci = 0; ci < 128; ++ci)
        acc = fmaf(w2sum[j * 128 + ci], s_sh[ci], acc);
    stats[S_BIAS2 + j] = acc;
}

// ---------------- K scale: apack *= BN1 scale (per input channel), in place ----------------
// Deterministic per call: k_prep rewrites apack raw before this every launch.
__global__ __launch_bounds__(256) void k_scale(_Float16* __restrict__ apack,
                                               const float* __restrict__ stats) {
    int tid = threadIdx.x, l = tid & 63;
    int f = blockIdx.x * 4 + (tid >> 6);
    int s = (f >> 3) & 3;
    int cbase = 32 * s + (l >> 4) * 8;
    _Float16* p = apack + (f * 64 + l) * 8;
#pragma unroll
    for (int j = 0; j < 8; ++j)
        p[j] = (_Float16)((float)p[j] * stats[S_BN1_SC + cbase + j]);
}

// ---------------- K3: 2 edges/block (best measured: 148us); raw y2pre -> LDS (pure copy),
// conv2 MFMA (BN1 folded in A) -> y3 t-major [44][128] + BN2 stats.
// [LDS staging is load-bearing: LDS-free variant regressed 148->276 us (L1 thrash).]
// [2-edge > 1-edge: second edge-wave's A-frags hit L1 -> halves L2 A-traffic. 4-edge loses
//  to the LDS-occupancy cliff. This tile shape is the measured optimum.] ----------------
__global__ __launch_bounds__(256) void k_conv2(_Float16* __restrict__ y23,
                                               const _Float16* __restrict__ apack,
                                               const float* __restrict__ stats,
                                               float* rep2) {
    __shared__ __align__(16) _Float16 s_y2t[2][52 * 136];
    int tid = threadIdx.x;
    int be0 = blockIdx.x * 2;
    for (int i = tid; i < 544; i += 256) {
        int ed = i / 272, rem = i - ed * 272;
        ((int*)(&s_y2t[ed][48 * 136]))[rem] = 0;
    }
    for (int i = tid; i < 1536; i += 256) {
        int ed = i / 768, rem = i - ed * 768;
        int row = rem >> 4, c0 = (rem & 15) * 8;
        *(f16x8*)(&s_y2t[ed][row * 136 + c0]) =
            *(const f16x8*)(y23 + (long long)(be0 + ed) * 6144 + rem * 8);
    }
    __syncthreads();
    int w = tid >> 6, lane = tid & 63;
    int quad = lane >> 4, l15 = lane & 15;
    int g = w & 1, e = w >> 1;
    f32x4 acc[4][3];
#pragma unroll
    for (int m = 0; m < 4; ++m)
#pragma unroll
        for (int nt = 0; nt < 3; ++nt) acc[m][nt] = (f32x4){0.f, 0.f, 0.f, 0.f};
    const f16x8* Ap = (const f16x8*)apack;
    const char* base = (const char*)&s_y2t[e][0];
#pragma unroll
    for (int k = 0; k < 5; ++k) {
#pragma unroll
        for (int s = 0; s < 4; ++s) {
            f16x8 am[4];
#pragma unroll
            for (int m = 0; m < 4; ++m)
                am[m] = Ap[((k * 4 + s) * 8 + g * 4 + m) * 64 + lane];
#pragma unroll
            for (int nt = 0; nt < 3; ++nt) {
                f16x8 bfr = *(const f16x8*)(base + (nt * 16 + l15 + k) * 272 + 64 * s + quad * 16);
#pragma unroll
                for (int m = 0; m < 4; ++m)
                    acc[m][nt] = __builtin_amdgcn_mfma_f32_16x16x32_f16(am[m], bfr, acc[m][nt], 0, 0, 0);
            }
        }
    }
    // epilogue: bias2 + relu, store y3 t-major [44][128] (f16x4), BN2 stats
    int be = be0 + e;
    _Float16* y3 = y23 + (long long)be * 6144;
    float* rep = rep2 + (be & (NREP - 1)) * 256;
#pragma unroll
    for (int m = 0; m < 4; ++m) {
        int co0 = (g * 4 + m) * 16 + quad * 4;
        float4 bs = *(const float4*)(stats + S_BIAS2 + co0);
        float ssum[4] = {0.f, 0.f, 0.f, 0.f}, qsum[4] = {0.f, 0.f, 0.f, 0.f};
#pragma unroll
        for (int nt = 0; nt < 3; ++nt) {
            int t = nt * 16 + l15;
            if (t < 44) {
                float v0 = fmaxf(acc[m][nt][0] + bs.x, 0.f);
                float v1 = fmaxf(acc[m][nt][1] + bs.y, 0.f);
                float v2 = fmaxf(acc[m][nt][2] + bs.z, 0.f);
                float v3 = fmaxf(acc[m][nt][3] + bs.w, 0.f);
                f16x4 o = {(_Float16)v0, (_Float16)v1, (_Float16)v2, (_Float16)v3};
                *(f16x4*)(y3 + t * 128 + co0) = o;
                ssum[0] += v0; qsum[0] += v0 * v0;
                ssum[1] += v1; qsum[1] += v1 * v1;
                ssum[2] += v2; qsum[2] += v2 * v2;
                ssum[3] += v3; qsum[3] += v3 * v3;
            }
        }
#pragma unroll
        for (int r = 0; r < 4; ++r) {
            float s = ssum[r], q = qsum[r];
            s += __shfl_xor(s, 1); s += __shfl_xor(s, 2); s += __shfl_xor(s, 4); s += __shfl_xor(s, 8);
            q += __shfl_xor(q, 1); q += __shfl_xor(q, 2); q += __shfl_xor(q, 4); q += __shfl_xor(q, 8);
            if (l15 == 0) {
                atomicAdd(&rep[co0 + r], s);
                atomicAdd(&rep[128 + co0 + r], q);
            }
        }
    }
}

// ---------------- K5: BN2 apply + attention-pool -> x [BE][128] (y3 t-major input) ----------------
__global__ __launch_bounds__(256) void k_predatt(const _Float16* __restrict__ y23,
                                                 const float* __restrict__ stats,
                                                 const float* __restrict__ att_w,
                                                 const float* __restrict__ att_b,
                                                 const float* __restrict__ pwt,
                                                 const float* __restrict__ pred_b,
                                                 float* __restrict__ x) {
    __shared__ float h[44 * 132];   // h[t][c], stride 132 (pad 4)
    __shared__ float s_att[48];
    __shared__ float s_p1[256];
    __shared__ float s_p2[256];
    __shared__ float s_sc[128], s_sh[128];
    int be = blockIdx.x, tid = threadIdx.x;
    if (tid < 128) {
        s_sc[tid] = stats[S_BN2_SC + tid];
        s_sh[tid] = stats[S_BN2_SC + 128 + tid];
    }
    __syncthreads();
    const _Float16* yp = y23 + (long long)be * 6144;
    for (int i = tid; i < 704; i += 256) {   // 44 rows x 16 chunks of 8
        int t = i >> 4, c0 = (i & 15) * 8;
        f16x8 v = *(const f16x8*)(yp + i * 8);
        float4 a, bq;
        a.x = fmaf((float)v[0], s_sc[c0 + 0], s_sh[c0 + 0]);
        a.y = fmaf((float)v[1], s_sc[c0 + 1], s_sh[c0 + 1]);
        a.z = fmaf((float)v[2], s_sc[c0 + 2], s_sh[c0 + 2]);
        a.w = fmaf((float)v[3], s_sc[c0 + 3], s_sh[c0 + 3]);
        bq.x = fmaf((float)v[4], s_sc[c0 + 4], s_sh[c0 + 4]);
        bq.y = fmaf((float)v[5], s_sc[c0 + 5], s_sh[c0 + 5]);
        bq.z = fmaf((float)v[6], s_sc[c0 + 6], s_sh[c0 + 6]);
        bq.w = fmaf((float)v[7], s_sc[c0 + 7], s_sh[c0 + 7]);
        *(float4*)(&h[t * 132 + c0]) = a;
        *(float4*)(&h[t * 132 + c0 + 4]) = bq;
    }
    __syncthreads();
    int w = tid >> 6, lane = tid & 63;
    {
        float aw0 = att_w[lane], aw1 = att_w[64 + lane];
        for (int tt = 0; tt < 11; ++tt) {
            int t = w * 11 + tt;
            float p = h[t * 132 + lane] * aw0 + h[t * 132 + 64 + lane] * aw1;
            p += __shfl_xor(p, 1); p += __shfl_xor(p, 2); p += __shfl_xor(p, 4);
            p += __shfl_xor(p, 8); p += __shfl_xor(p, 16); p += __shfl_xor(p, 32);
            if (lane == 0) s_att[t] = p + att_b[0];
        }
    }
    __syncthreads();
    if (w == 0) {
        float v = (lane < 44) ? s_att[lane] : -1e30f;
        float m = v;
        m = fmaxf(m, __shfl_xor(m, 1)); m = fmaxf(m, __shfl_xor(m, 2));
        m = fmaxf(m, __shfl_xor(m, 4)); m = fmaxf(m, __shfl_xor(m, 8));
        m = fmaxf(m, __shfl_xor(m, 16)); m = fmaxf(m, __shfl_xor(m, 32));
        float ev = (lane < 44) ? expf(v - m) : 0.f;
        float ss = ev;
        ss += __shfl_xor(ss, 1); ss += __shfl_xor(ss, 2); ss += __shfl_xor(ss, 4);
        ss += __shfl_xor(ss, 8); ss += __shfl_xor(ss, 16); ss += __shfl_xor(ss, 32);
        if (lane < 44) s_att[lane] = ev / ss;
    }
    __syncthreads();
    {
        int c = tid & 127, hh = tid >> 7;
        float a = 0.f;
        for (int t = hh * 22; t < hh * 22 + 22; ++t) a = fmaf(h[t * 132 + c], s_att[t], a);
        s_p1[tid] = a;
    }
    __syncthreads();
    {
        int o = tid & 127, hh = tid >> 7;
        float a = 0.f;
        for (int c = hh * 64; c < hh * 64 + 64; ++c) {
            float hw = s_p1[c] + s_p1[128 + c];
            a = fmaf(pwt[c * 128 + o], hw, a);
        }
        s_p2[tid] = a;
    }
    __syncthreads();
    if (tid < 128) {
        float a = s_p2[tid] + s_p2[128 + tid] + pred_b[tid];
        x[(long long)be * 128 + tid] = a * (1.0f / 44.0f);
    }
}

// ---------------- fused 2-layer MFMA MLP (128->128->128), 64 rows/block ----------------
// in f32 -> L1(ELU) kept in LDS f16 -> L2(ELU) -> out f32 + fused col stats.
__global__ __launch_bounds__(256) void k_mlp2x(const float* __restrict__ in,
                                               const _Float16* __restrict__ wp1,
                                               const float* __restrict__ b1,
                                               const _Float16* __restrict__ wp2,
                                               const float* __restrict__ b2,
                                               float* __restrict__ out,
                                               float* __restrict__ repm) {
    __shared__ __align__(16) _Float16 s_in[64 * 136];
    __shared__ __align__(16) _Float16 s_mid[64 * 136];
    int tid = threadIdx.x;
    long long r0 = (long long)blockIdx.x * 64;
    {
        const float4* src = (const float4*)(in + r0 * 128);
        for (int i = tid; i < 2048; i += 256) {
            int row = i >> 5, c0 = (i & 31) * 4;
            float4 v = src[i];
            f16x4 o = {(_Float16)v.x, (_Float16)v.y, (_Float16)v.z, (_Float16)v.w};
            *(f16x4*)(&s_in[row * 136 + c0]) = o;
        }
    }
    __syncthreads();
    int w = tid >> 6, lane = tid & 63, quad = lane >> 4, l15 = lane & 15;
    // layer 1
    {
        f32x4 acc[2][4];
#pragma unroll
        for (int m = 0; m < 2; ++m)
#pragma unroll
            for (int nt = 0; nt < 4; ++nt) acc[m][nt] = (f32x4){0.f, 0.f, 0.f, 0.f};
        const f16x8* Ap = (const f16x8*)wp1;
#pragma unroll
        for (int s = 0; s < 4; ++s) {
            f16x8 a0 = Ap[(s * 8 + 2 * w) * 64 + lane];
            f16x8 a1 = Ap[(s * 8 + 2 * w + 1) * 64 + lane];
#pragma unroll
            for (int nt = 0; nt < 4; ++nt) {
                f16x8 bfr = *(const f16x8*)((const char*)s_in + (nt * 16 + l15) * 272 + 64 * s + quad * 16);
                acc[0][nt] = __builtin_amdgcn_mfma_f32_16x16x32_f16(a0, bfr, acc[0][nt], 0, 0, 0);
                acc[1][nt] = __builtin_amdgcn_mfma_f32_16x16x32_f16(a1, bfr, acc[1][nt], 0, 0, 0);
            }
        }
#pragma unroll
        for (int m = 0; m < 2; ++m) {
            int j0 = (2 * w + m) * 16 + quad * 4;
            float4 bs = *(const float4*)(b1 + j0);
#pragma unroll
            for (int nt = 0; nt < 4; ++nt) {
                int row = nt * 16 + l15;
                f16x4 o = {(_Float16)eluf(acc[m][nt][0] + bs.x),
                           (_Float16)eluf(acc[m][nt][1] + bs.y),
                           (_Float16)eluf(acc[m][nt][2] + bs.z),
                           (_Float16)eluf(acc[m][nt][3] + bs.w)};
                *(f16x4*)(&s_mid[row * 136 + j0]) = o;
            }
        }
    }
    __syncthreads();
    // layer 2 + stats
    {
        f32x4 acc[2][4];
#pragma unroll
        for (int m = 0; m < 2; ++m)
#pragma unroll
            for (int nt = 0; nt < 4; ++nt) acc[m][nt] = (f32x4){0.f, 0.f, 0.f, 0.f};
        const f16x8* Ap = (const f16x8*)wp2;
#pragma unroll
        for (int s = 0; s < 4; ++s) {
            f16x8 a0 = Ap[(s * 8 + 2 * w) * 64 + lane];
            f16x8 a1 = Ap[(s * 8 + 2 * w + 1) * 64 + lane];
#pragma unroll
            for (int nt = 0; nt < 4; ++nt) {
                f16x8 bfr = *(const f16x8*)((const char*)s_mid + (nt * 16 + l15) * 272 + 64 * s + quad * 16);
                acc[0][nt] = __builtin_amdgcn_mfma_f32_16x16x32_f16(a0, bfr, acc[0][nt], 0, 0, 0);
                acc[1][nt] = __builtin_amdgcn_mfma_f32_16x16x32_f16(a1, bfr, acc[1][nt], 0, 0, 0);
            }
        }
#pragma unroll
        for (int m = 0; m < 2; ++m) {
            int j0 = (2 * w + m) * 16 + quad * 4;
            float4 bs = *(const float4*)(b2 + j0);
            float ss[4] = {0.f, 0.f, 0.f, 0.f}, qq[4] = {0.f, 0.f, 0.f, 0.f};
#pragma unroll
            for (int nt = 0; nt < 4; ++nt) {
                int row = nt * 16 + l15;
                float v0 = eluf(acc[m][nt][0] + bs.x);
                float v1 = eluf(acc[m][nt][1] + bs.y);
                float v2 = eluf(acc[m][nt][2] + bs.z);
                float v3 = eluf(acc[m][nt][3] + bs.w);
                float4 o = {v0, v1, v2, v3};
                *(float4*)(out + (r0 + row) * 128 + j0) = o;
                ss[0] += v0; qq[0] += v0 * v0;
                ss[1] += v1; qq[1] += v1 * v1;
                ss[2] += v2; qq[2] += v2 * v2;
                ss[3] += v3; qq[3] += v3 * v3;
            }
            float* rep = repm + (blockIdx.x & (NREP - 1)) * 256;
#pragma unroll
            for (int r = 0; r < 4; ++r) {
                float s = ss[r], q = qq[r];
                s += __shfl_xor(s, 1); s += __shfl_xor(s, 2); s += __shfl_xor(s, 4); s += __shfl_xor(s, 8);
                q += __shfl_xor(q, 1); q += __shfl_xor(q, 2); q += __shfl_xor(q, 4); q += __shfl_xor(q, 8);
                if (l15 == 0) {
                    atomicAdd(&rep[j0 + r], s);
                    atomicAdd(&rep[128 + j0 + r], q);
                }
            }
        }
    }
}

// ---------------- fused mlp3: gather-concat [send|recv|skip] (K=384) -> L1(ELU, LDS) -> L2(ELU) -> f32 + stats ----------------
__global__ __launch_bounds__(256) void k_mlp3x(const float* __restrict__ xn,
                                               const float* __restrict__ bufB,
                                               const int* __restrict__ sidx,
                                               const int* __restrict__ ridx,
                                               const float* __restrict__ stats,
                                               const _Float16* __restrict__ wp1,
                                               const float* __restrict__ b1,
                                               const _Float16* __restrict__ wp2,
                                               const float* __restrict__ b2,
                                               float* __restrict__ out,
                                               float* __restrict__ repm) {
    __shared__ __align__(16) _Float16 s_b[64 * 392];
    __shared__ __align__(16) _Float16 s_mid[64 * 136];
    __shared__ float s_st[4][128];
    __shared__ int s_s[64], s_r[64];
    int tid = threadIdx.x;
    long long r0 = (long long)blockIdx.x * 64;
    if (tid < 128) {
        s_st[0][tid] = stats[S_M2_SC + tid];
        s_st[1][tid] = stats[S_M2_SC + 128 + tid];
        s_st[2][tid] = stats[S_M1_SC + tid];
        s_st[3][tid] = stats[S_M1_SC + 128 + tid];
    }
    if (tid < 64) {
        int r = (int)r0 + tid, b = r / EE, ed = r - b * EE;
        s_s[tid] = (b * NN + sidx[ed]) * 128;
        s_r[tid] = (b * NN + ridx[ed]) * 128;
    }
    __syncthreads();
    for (int i = tid; i < 8192; i += 256) {
        int row = i >> 7, j = i & 127;
        float sc2 = s_st[0][j], sh2 = s_st[1][j];
        s_b[row * 392 + j] = (_Float16)fmaf(xn[s_s[row] + j], sc2, sh2);
        s_b[row * 392 + 128 + j] = (_Float16)fmaf(xn[s_r[row] + j], sc2, sh2);
        s_b[row * 392 + 256 + j] = (_Float16)fmaf(bufB[(r0 + row) * 128 + j], s_st[2][j], s_st[3][j]);
    }
    __syncthreads();
    int w = tid >> 6, lane = tid & 63, quad = lane >> 4, l15 = lane & 15;
    // layer 1 (K=384)
    {
        f32x4 acc[2][4];
#pragma unroll
        for (int m = 0; m < 2; ++m)
#pragma unroll
            for (int nt = 0; nt < 4; ++nt) acc[m][nt] = (f32x4){0.f, 0.f, 0.f, 0.f};
        const f16x8* Ap = (const f16x8*)wp1;
#pragma unroll
        for (int s = 0; s < 12; ++s) {
            f16x8 a0 = Ap[(s * 8 + 2 * w) * 64 + lane];
            f16x8 a1 = Ap[(s * 8 + 2 * w + 1) * 64 + lane];
#pragma unroll
            for (int nt = 0; nt < 4; ++nt) {
                f16x8 bfr = *(const f16x8*)((const char*)s_b + (nt * 16 + l15) * 784 + 64 * s + quad * 16);
                acc[0][nt] = __builtin_amdgcn_mfma_f32_16x16x32_f16(a0, bfr, acc[0][nt], 0, 0, 0);
                acc[1][nt] = __builtin_amdgcn_mfma_f32_16x16x32_f16(a1, bfr, acc[1][nt], 0, 0, 0);
            }
        }
#pragma unroll
        for (int m = 0; m < 2; ++m) {
            int j0 = (2 * w + m) * 16 + quad * 4;
            float4 bs = *(const float4*)(b1 + j0);
#pragma unroll
            for (int nt = 0; nt < 4; ++nt) {
                int row = nt * 16 + l15;
                f16x4 o = {(_Float16)eluf(acc[m][nt][0] + bs.x),
                           (_Float16)eluf(acc[m][nt][1] + bs.y),
                           (_Float16)eluf(acc[m][nt][2] + bs.z),
                           (_Float16)eluf(acc[m][nt][3] + bs.w)};
                *(f16x4*)(&s_mid[row * 136 + j0]) = o;
            }
        }
    }
    __syncthreads();
    // layer 2 + stats
    {
        f32x4 acc[2][4];
#pragma unroll
        for (int m = 0; m < 2; ++m)
#pragma unroll
            for (int nt = 0; nt < 4; ++nt) acc[m][nt] = (f32x4){0.f, 0.f, 0.f, 0.f};
        const f16x8* Ap = (const f16x8*)wp2;
#pragma unroll
        for (int s = 0; s < 4; ++s) {
            f16x8 a0 = Ap[(s * 8 + 2 * w) * 64 + lane];
            f16x8 a1 = Ap[(s * 8 + 2 * w + 1) * 64 + lane];
#pragma unroll
            for (int nt = 0; nt < 4; ++nt) {
                f16x8 bfr = *(const f16x8*)((const char*)s_mid + (nt * 16 + l15) * 272 + 64 * s + quad * 16);
                acc[0][nt] = __builtin_amdgcn_mfma_f32_16x16x32_f16(a0, bfr, acc[0][nt], 0, 0, 0);
                acc[1][nt] = __builtin_amdgcn_mfma_f32_16x16x32_f16(a1, bfr, acc[1][nt], 0, 0, 0);
            }
        }
#pragma unroll
        for (int m = 0; m < 2; ++m) {
            int j0 = (2 * w + m) * 16 + quad * 4;
            float4 bs = *(const float4*)(b2 + j0);
            float ss[4] = {0.f, 0.f, 0.f, 0.f}, qq[4] = {0.f, 0.f, 0.f, 0.f};
#pragma unroll
            for (int nt = 0; nt < 4; ++nt) {
                int row = nt * 16 + l15;
                float v0 = eluf(acc[m][nt][0] + bs.x);
                float v1 = eluf(acc[m][nt][1] + bs.y);
                float v2 = eluf(acc[m][nt][2] + bs.z);
                float v3 = eluf(acc[m][nt][3] + bs.w);
                float4 o = {v0, v1, v2, v3};
                *(float4*)(out + (r0 + row) * 128 + j0) = o;
                ss[0] += v0; qq[0] += v0 * v0;
                ss[1] += v1; qq[1] += v1 * v1;
                ss[2] += v2; qq[2] += v2 * v2;
                ss[3] += v3; qq[3] += v3 * v3;
            }
            float* rep = repm + (blockIdx.x & (NREP - 1)) * 256;
#pragma unroll
            for (int r = 0; r < 4; ++r) {
                float s = ss[r], q = qq[r];
                s += __shfl_xor(s, 1); s += __shfl_xor(s, 2); s += __shfl_xor(s, 4); s += __shfl_xor(s, 8);
                q += __shfl_xor(q, 1); q += __shfl_xor(q, 2); q += __shfl_xor(q, 4); q += __shfl_xor(q, 8);
                if (l15 == 0) {
                    atomicAdd(&rep[j0 + r], s);
                    atomicAdd(&rep[128 + j0 + r], q);
                }
            }
        }
    }
}

// ---------------- edge2node scatter-mean with inline BN-M1 ----------------
__global__ __launch_bounds__(128) void k_e2n(const float* __restrict__ bufB,
                                             const int* __restrict__ inc,
                                             const float* __restrict__ stats,
                                             float* __restrict__ xn) {
    int bn = blockIdx.x;
    int b = bn / NN, n = bn - b * NN;
    int j = threadIdx.x;
    float sc = stats[S_M1_SC + j], sh = stats[S_M1_SC + 128 + j];
    float s = 0.f;
    for (int k = 0; k < NN - 1; ++k) {
        int e = inc[n * (NN - 1) + k];
        s += bufB[(long long)(b * EE + e) * 128 + j];
    }
    xn[bn * 128 + j] = (s * sc + (float)(NN - 1) * sh) * (1.0f / (float)NN);
}

// ---------------- BN3 apply + fc_out (128 -> 16) ----------------
__global__ __launch_bounds__(256) void k_fcout(const float* __restrict__ h2,
                                               const float* __restrict__ stats,
                                               const float* __restrict__ fcw,
                                               const float* __restrict__ fcb,
                                               float* __restrict__ out) {
    __shared__ float s_x[16 * 129];
    __shared__ float s_w[16 * 129];
    int r0 = blockIdx.x * 16;
    int tid = threadIdx.x;
    for (int i = tid; i < 16 * 128; i += 256) {
        int rr = i >> 7, j = i & 127;
        s_x[rr * 129 + j] = fmaf(h2[(long long)(r0 + rr) * 128 + j],
                                 stats[S_M3_SC + j], stats[S_M3_SC + 128 + j]);
    }
    for (int i = tid; i < 16 * 128; i += 256) {
        int o = i >> 7, j = i & 127;
        s_w[o * 129 + j] = fcw[i];
    }
    __syncthreads();
    int rl = tid >> 4, o = tid & 15;
    float a = fcb[o];
    for (int j = 0; j < 128; ++j) a = fmaf(s_x[rl * 129 + j], s_w[o * 129 + j], a);
    out[(long long)(r0 + rl) * 16 + o] = a;
}

// ---------------- host launcher ----------------
extern "C" void kernel_launch(void* const* d_in, const int* in_sizes, int n_in,
                              void* d_out, int out_size, void* d_ws, size_t ws_size,
                              hipStream_t stream) {
    const float* inputs = (const float*)d_in[0];
    const float* rel_rec = (const float*)d_in[1];
    const float* rel_send = (const float*)d_in[2];
    const float* conv1_w = (const float*)d_in[3];
    const float* conv1_b = (const float*)d_in[4];
    const float* bn1_g = (const float*)d_in[5];
    const float* bn1_b = (const float*)d_in[6];
    const float* conv2_w = (const float*)d_in[7];
    const float* conv2_b = (const float*)d_in[8];
    const float* bn2_g = (const float*)d_in[9];
    const float* bn2_b = (const float*)d_in[10];
    const float* pred_w = (const float*)d_in[11];
    const float* pred_b = (const float*)d_in[12];
    const float* att_w = (const float*)d_in[13];
    const float* att_b = (const float*)d_in[14];
    const float* m1w1 = (const float*)d_in[15];
    const float* m1b1 = (const float*)d_in[16];
    const float* m1w2 = (const float*)d_in[17];
    const float* m1b2 = (const float*)d_in[18];
    const float* m1g = (const float*)d_in[19];
    const float* m1bb = (const float*)d_in[20];
    const float* m2w1 = (const float*)d_in[21];
    const float* m2b1 = (const float*)d_in[22];
    const float* m2w2 = (const float*)d_in[23];
    const float* m2b2 = (const float*)d_in[24];
    const float* m2g = (const float*)d_in[25];
    const float* m2bb = (const float*)d_in[26];
    const float* m3w1 = (const float*)d_in[27];
    const float* m3b1 = (const float*)d_in[28];
    const float* m3w2 = (const float*)d_in[29];
    const float* m3b2 = (const float*)d_in[30];
    const float* m3g = (const float*)d_in[31];
    const float* m3bb = (const float*)d_in[32];
    const float* fcw = (const float*)d_in[33];
    const float* fcb = (const float*)d_in[34];

    char* ws = (char*)d_ws;
    float* stats = (float*)(ws + OFF_STATS);
    int* sidx = (int*)(ws + OFF_SIDX);
    int* ridx = (int*)(ws + OFF_RIDX);
    int* inc = (int*)(ws + OFF_INC);
    _Float16* y23 = (_Float16*)(ws + OFF_Y23);
    float* x = (float*)(ws + OFF_X);
    float* bufB = (float*)(ws + OFF_BUFB);
    float* xn = (float*)(ws + OFF_XN);
    _Float16* apack = (_Float16*)(ws + OFF_APACK);
    _Float16* apack1 = (_Float16*)(ws + OFF_APACK1);
    float* pwt = (float*)(ws + OFF_PWT);
    float* w2sum = (float*)(ws + OFF_W2SUM);
    float* rep1 = (float*)(ws + OFF_REP1);
    float* rep2 = (float*)(ws + OFF_REP2);
    float* repm = (float*)(ws + OFF_REPM);
    _Float16* mp = (_Float16*)(ws + OFF_MP);
    float* outp = (float*)d_out;

    hipLaunchKernelGGL(k_prep, dim3(125), dim3(256), 0, stream,
                       rel_rec, rel_send, conv2_w, conv1_w, pred_w,
                       m1w1, m1w2, m2w1, m2w2, m3w1, m3w2,
                       apack, apack1, pwt, w2sum, mp, rep1, rep2, repm, sidx, ridx, inc);
    hipLaunchKernelGGL(k_conv1_stats, dim3(BE), dim3(256), 0, stream,
                       inputs, apack1, conv1_b, sidx, ridx, rep1, y23);
    hipLaunchKernelGGL(k_finalize_bn1, dim3(1), dim3(128), 0, stream,
                       rep1, stats, bn1_g, bn1_b, w2sum, conv2_b, 1.0f / (float)(BE * L1));
    hipLaunchKernelGGL(k_scale, dim3(40), dim3(256), 0, stream, apack, stats);
    hipLaunchKernelGGL(k_conv2, dim3(BE / 2), dim3(256), 0, stream,
                       y23, apack, stats, rep2);
    hipLaunchKernelGGL(k_finalize_rep, dim3(1), dim3(128), 0, stream,
                       rep2, stats, S_BN2_SC, bn2_g, bn2_b, 1.0f / (float)(BE * L2));
    hipLaunchKernelGGL(k_predatt, dim3(BE), dim3(256), 0, stream,
                       y23, stats, att_w, att_b, pwt, pred_b, x);
    // mlp1 (fused 2-layer MFMA)
    hipLaunchKernelGGL(k_mlp2x, dim3(BE / 64), dim3(256), 0, stream,
                       x, mp + MP_M1W1, m1b1, mp + MP_M1W2, m1b2, bufB, repm);
    hipLaunchKernelGGL(k_finalize_rep, dim3(1), dim3(128), 0, stream,
                       repm, stats, S_M1_SC, m1g, m1bb, 1.0f / (float)BE);
    // edge2node (BN-M1 inline) + mlp2 (fused)
    hipLaunchKernelGGL(k_e2n, dim3(BB * NN), dim3(128), 0, stream, bufB, inc, stats, xn);
    hipLaunchKernelGGL(k_mlp2x, dim3(BB * NN / 64), dim3(256), 0, stream,
                       xn, mp + MP_M2W1, m2b1, mp + MP_M2W2, m2b2, xn, repm);
    hipLaunchKernelGGL(k_finalize_rep, dim3(1), dim3(128), 0, stream,
                       repm, stats, S_M2_SC, m2g, m2bb, 1.0f / (float)(BB * NN));
    // node2edge + mlp3 (fused gather + 2-layer)
    hipLaunchKernelGGL(k_mlp3x, dim3(BE / 64), dim3(256), 0, stream,
                       xn, bufB, sidx, ridx, stats, mp + MP_M3W1, m3b1, mp + MP_M3W2, m3b2,
                       bufB, repm);
    hipLaunchKernelGGL(k_finalize_rep, dim3(1), dim3(128), 0, stream,
                       repm, stats, S_M3_SC, m3g, m3bb, 1.0f / (float)BE);
    // fc_out (BN-M3 inline)
    hipLaunchKernelGGL(k_fcout, dim3(BE / 16), dim3(256), 0, stream, bufB, stats, fcw, fcb, outp);
    (void)in_sizes; (void)n_in; (void)out_size; (void)ws_size;
}